// Round 5
// baseline (1550.492 us; speedup 1.0000x reference)
//
#include <hip/hip_runtime.h>
#include <stdint.h>

typedef unsigned long long u64;
typedef __attribute__((ext_vector_type(8))) short bf16x8;   // 8 bf16 = 4 VGPRs
typedef __attribute__((ext_vector_type(4))) float f32x4;

__device__ __forceinline__ unsigned short f2bf(float f) {
    unsigned x = __float_as_uint(f);
    unsigned r = (x + 0x7fffu + ((x >> 16) & 1u)) >> 16;   // RNE
    return (unsigned short)r;
}
__device__ __forceinline__ constexpr int cmax2(int a, int b) { return a > b ? a : b; }

// Wave64 max-reduce of a non-negative f32 at VALU speed (DPP, no LDS hops).
__device__ __forceinline__ float wave_max_dpp(float v) {
#define DPP_MAX_STEP(ctrl)                                                     \
    v = fmaxf(v, __int_as_float(__builtin_amdgcn_update_dpp(                   \
               0, __float_as_int(v), (ctrl), 0xf, 0xf, true)))
    DPP_MAX_STEP(0xB1);   // quad_perm xor1
    DPP_MAX_STEP(0x4E);   // quad_perm xor2
    DPP_MAX_STEP(0x141);  // row_half_mirror xor4
    DPP_MAX_STEP(0x140);  // row_mirror xor8
    DPP_MAX_STEP(0x142);  // row_bcast15
    DPP_MAX_STEP(0x143);  // row_bcast31
#undef DPP_MAX_STEP
    return __int_as_float(__builtin_amdgcn_readlane(__float_as_int(v), 63));
}

// One row-local butterfly step: lexicographic u64 max with 3-float payload.
template <int CTRL>
__device__ __forceinline__ void bfly_step(unsigned& lo, unsigned& hi,
                                          float& x, float& y, float& z) {
    const unsigned olo = (unsigned)__builtin_amdgcn_update_dpp(0, (int)lo, CTRL, 0xf, 0xf, true);
    const unsigned ohi = (unsigned)__builtin_amdgcn_update_dpp(0, (int)hi, CTRL, 0xf, 0xf, true);
    const int oxi = __builtin_amdgcn_update_dpp(0, __float_as_int(x), CTRL, 0xf, 0xf, true);
    const int oyi = __builtin_amdgcn_update_dpp(0, __float_as_int(y), CTRL, 0xf, 0xf, true);
    const int ozi = __builtin_amdgcn_update_dpp(0, __float_as_int(z), CTRL, 0xf, 0xf, true);
    const bool g = (ohi > hi) || (ohi == hi && olo > lo);
    lo = g ? olo : lo;
    hi = g ? ohi : hi;
    x = g ? __int_as_float(oxi) : x;
    y = g ? __int_as_float(oyi) : y;
    z = g ? __int_as_float(ozi) : z;
}

// ---------------------------------------------------------------------------
// Kernel 1: farthest point sampling (f32 I/O). One block per batch.
// 1024 threads (16 waves), 4 pts/thread in registers; NO point LDS at all.
// Bit-exact vs numpy: ((dx*dx+dy*dy)+dz*dz), fminf chain, argmax-first-tie.
// Winner coords travel with the key: wave slot = {distbits, 4095-idx, x,y,z};
// cross-wave winner via row-local DPP butterfly over the 16 slot entries.
// ---------------------------------------------------------------------------
__global__ __launch_bounds__(1024) void fps_kernel(const float* __restrict__ xyz,
                                                   float* __restrict__ newxyz) {
    const int b = blockIdx.x;
    const int t = threadIdx.x;
    const int lane = t & 63;
    const int wave = t >> 6;
    __shared__ unsigned skeylo[2][16], skeyhi[2][16];
    __shared__ float ssx[2][16], ssy[2][16], ssz[2][16];

    float px[4], py[4], pz[4], dist[4];
    {
        union { float4 v[3]; float f[12]; } u;
        const float4* src =
            reinterpret_cast<const float4*>(xyz + (size_t)b * 12288) + t * 3;
#pragma unroll
        for (int w = 0; w < 3; ++w) u.v[w] = src[w];
#pragma unroll
        for (int i = 0; i < 4; ++i) {
            px[i] = u.f[3 * i + 0];
            py[i] = u.f[3 * i + 1];
            pz[i] = u.f[3 * i + 2];
            dist[i] = 1e10f;
        }
    }
    // first centroid = point 0 (uniform broadcast load, L2-cached)
    const float* p0 = xyz + (size_t)b * 12288;
    float cx = p0[0], cy = p0[1], cz = p0[2];

    for (int k = 0; k < 1024; ++k) {
        if (t == 0) {
            const size_t o = ((size_t)b * 1024 + k) * 3;
            newxyz[o + 0] = cx; newxyz[o + 1] = cy; newxyz[o + 2] = cz;
        }
#pragma unroll
        for (int i = 0; i < 4; ++i) {
            const float dx = px[i] - cx, dy = py[i] - cy, dz = pz[i] - cz;
            const float d = __fadd_rn(__fadd_rn(__fmul_rn(dx, dx), __fmul_rn(dy, dy)),
                                      __fmul_rn(dz, dz));
            dist[i] = fminf(dist[i], d);
        }
        // thread-local best (smallest index on tie) + its coords
        const float bv = fmaxf(fmaxf(dist[0], dist[1]), fmaxf(dist[2], dist[3]));
        int bj = 3;
        float bx = px[3], by = py[3], bz = pz[3];
#pragma unroll
        for (int i = 2; i >= 0; --i) {
            const bool e = (dist[i] == bv);
            bj = e ? i : bj;
            bx = e ? px[i] : bx;
            by = e ? py[i] : by;
            bz = e ? pz[i] : bz;
        }
        const int myidx = t * 4 + bj;

        // wave-level: DPP max, first matching lane = smallest global idx
        const float wmax = wave_max_dpp(bv);
        const u64 mask = __ballot(bv == wmax);
        const int fl = (int)__builtin_ctzll(mask);
        const int widx = __builtin_amdgcn_readlane(myidx, fl);
        const int wxi = __builtin_amdgcn_readlane(__float_as_int(bx), fl);
        const int wyi = __builtin_amdgcn_readlane(__float_as_int(by), fl);
        const int wzi = __builtin_amdgcn_readlane(__float_as_int(bz), fl);

        const int p = k & 1;
        if (lane == 0) {
            skeylo[p][wave] = (unsigned)(4095 - widx);
            skeyhi[p][wave] = __float_as_uint(wmax);
            ssx[p][wave] = __int_as_float(wxi);
            ssy[p][wave] = __int_as_float(wyi);
            ssz[p][wave] = __int_as_float(wzi);
        }
        __syncthreads();
        // every row of 16 lanes holds the 16 wave entries; butterfly them
        unsigned lo = skeylo[p][lane & 15];
        unsigned hi = skeyhi[p][lane & 15];
        float x = ssx[p][lane & 15];
        float y = ssy[p][lane & 15];
        float z = ssz[p][lane & 15];
        bfly_step<0xB1>(lo, hi, x, y, z);    // xor1
        bfly_step<0x4E>(lo, hi, x, y, z);    // xor2
        bfly_step<0x141>(lo, hi, x, y, z);   // xor4
        bfly_step<0x140>(lo, hi, x, y, z);   // xor8
        cx = x; cy = y; cz = z;
    }
}

// ---------------------------------------------------------------------------
// Kernel 2: ball query, all 3 radii in one pass (f32 in, u16 idx out).
// One wave per (b,s). Bit-exact predicate vs numpy (radius^2 folds to f32).
// ---------------------------------------------------------------------------
__global__ __launch_bounds__(256) void ballq_kernel(const float* __restrict__ xyz,
                                                    const float* __restrict__ newxyz,
                                                    unsigned short* __restrict__ idx0,
                                                    unsigned short* __restrict__ idx1,
                                                    unsigned short* __restrict__ idx2) {
    const int wave = threadIdx.x >> 6;
    const int lane = threadIdx.x & 63;
    const int g = blockIdx.x * 4 + wave;   // g = b*1024 + s
    const int b = g >> 10;

    const float* nc = newxyz + (size_t)g * 3;
    const float cx = nc[0], cy = nc[1], cz = nc[2];

    int cnt0 = 0, cnt1 = 0, cnt2 = 0;
    int f0 = 0, f1 = 0, f2 = 0;
    unsigned short* o0 = idx0 + (size_t)g * 16;
    unsigned short* o1 = idx1 + (size_t)g * 32;
    unsigned short* o2 = idx2 + (size_t)g * 128;
    const float* base = xyz + (size_t)b * 12288;

    for (int it = 0; it < 64; ++it) {
        const int j = it * 64 + lane;
        const float* p = base + j * 3;
        const float dx = p[0] - cx;
        const float dy = p[1] - cy;
        const float dz = p[2] - cz;
        const float d2 = __fadd_rn(__fadd_rn(__fmul_rn(dx, dx), __fmul_rn(dy, dy)),
                                   __fmul_rn(dz, dz));
        const bool p0 = d2 < 0.01f;   // f32(0.1*0.1)
        const bool p1 = d2 < 0.04f;   // f32(0.2*0.2)
        const bool p2 = d2 < 0.16f;   // f32(0.4*0.4)
        const u64 m0 = __ballot(p0);
        const u64 m1 = __ballot(p1);
        const u64 m2 = __ballot(p2);
        const u64 lower = (((u64)1) << lane) - 1;

        if (cnt0 < 16) {
            if (cnt0 == 0 && m0) f0 = it * 64 + __builtin_ctzll(m0);
            const int pos = cnt0 + (int)__builtin_popcountll(m0 & lower);
            if (p0 && pos < 16) o0[pos] = (unsigned short)j;
            cnt0 += (int)__builtin_popcountll(m0);
        }
        if (cnt1 < 32) {
            if (cnt1 == 0 && m1) f1 = it * 64 + __builtin_ctzll(m1);
            const int pos = cnt1 + (int)__builtin_popcountll(m1 & lower);
            if (p1 && pos < 32) o1[pos] = (unsigned short)j;
            cnt1 += (int)__builtin_popcountll(m1);
        }
        if (cnt2 < 128) {
            if (cnt2 == 0 && m2) f2 = it * 64 + __builtin_ctzll(m2);
            const int pos = cnt2 + (int)__builtin_popcountll(m2 & lower);
            if (p2 && pos < 128) o2[pos] = (unsigned short)j;
            cnt2 += (int)__builtin_popcountll(m2);
        }
        if (cnt0 >= 16 && cnt1 >= 32 && cnt2 >= 128) break;
    }
    for (int pos = cnt0 + lane; pos < 16; pos += 64) o0[pos] = (unsigned short)f0;
    for (int pos = cnt1 + lane; pos < 32; pos += 64) o1[pos] = (unsigned short)f1;
    for (int pos = cnt2 + lane; pos < 128; pos += 64) o2[pos] = (unsigned short)f2;
}

// ---------------------------------------------------------------------------
// MLP helpers
// ---------------------------------------------------------------------------
template <int Cin, int Kp, int Cout, int SW>
__device__ __forceinline__ void load_weights_part(const float* __restrict__ w,
                                                  const float* __restrict__ bias,
                                                  unsigned short* Wbuf, float* bbuf,
                                                  int tid, int noff, int ld) {
    for (int e = tid; e < Cout * Kp; e += 256) {
        const int n = e % Cout, k = e / Cout;
        Wbuf[n * SW + k] = (k < Cin) ? f2bf(w[k * ld + noff + n]) : (unsigned short)0;
    }
    for (int e = tid; e < Cout; e += 256) bbuf[e] = bias[noff + e];
}

// One wave computes MW rows x Cout cols of one layer.
// A (m89/m120): A[m=lane&15][k=quad*8+j]; B staged transposed [n][k] with
// n=lane&15, k=quad*8+j; C/D: col=lane&15, row=quad*4+reg.
template <int MW, int Kp, int Cout, int SIN, int SW, int SOUT, bool LAST>
__device__ __forceinline__ void layer_mfma(const unsigned short* __restrict__ src,
                                           unsigned short* __restrict__ dst,
                                           const unsigned short* __restrict__ Wbuf,
                                           const float* __restrict__ bbuf,
                                           float* __restrict__ Mx,
                                           int lane, int mslice) {
    constexpr int MT = MW / 16;
    constexpr int NT = Cout / 16;
    const int ml = lane & 15;
    const int quad = lane >> 4;

    f32x4 acc[MT][NT];
#pragma unroll
    for (int mt = 0; mt < MT; ++mt)
#pragma unroll
        for (int nt = 0; nt < NT; ++nt) acc[mt][nt] = (f32x4){0.f, 0.f, 0.f, 0.f};

#pragma unroll
    for (int ks = 0; ks < Kp; ks += 32) {
        bf16x8 afr[MT], bfr[NT];
#pragma unroll
        for (int mt = 0; mt < MT; ++mt)
            afr[mt] = *reinterpret_cast<const bf16x8*>(
                src + (mslice * MW + mt * 16 + ml) * SIN + ks + quad * 8);
#pragma unroll
        for (int nt = 0; nt < NT; ++nt)
            bfr[nt] = *reinterpret_cast<const bf16x8*>(
                Wbuf + (nt * 16 + ml) * SW + ks + quad * 8);
#pragma unroll
        for (int mt = 0; mt < MT; ++mt)
#pragma unroll
            for (int nt = 0; nt < NT; ++nt)
                acc[mt][nt] = __builtin_amdgcn_mfma_f32_16x16x32_bf16(
                    afr[mt], bfr[nt], acc[mt][nt], 0, 0, 0);
    }

#pragma unroll
    for (int nt = 0; nt < NT; ++nt) {
        const int col = nt * 16 + ml;
        const float bv = bbuf[col];
        if constexpr (!LAST) {
#pragma unroll
            for (int mt = 0; mt < MT; ++mt)
#pragma unroll
                for (int r = 0; r < 4; ++r) {
                    const float v = fmaxf(acc[mt][nt][r] + bv, 0.0f);
                    dst[(mslice * MW + mt * 16 + quad * 4 + r) * SOUT + col] = f2bf(v);
                }
        } else {
            float mx = 0.0f;   // relu floor folds into the max
#pragma unroll
            for (int mt = 0; mt < MT; ++mt)
#pragma unroll
                for (int r = 0; r < 4; ++r) mx = fmaxf(mx, acc[mt][nt][r] + bv);
            mx = fmaxf(mx, __shfl_xor(mx, 16, 64));
            mx = fmaxf(mx, __shfl_xor(mx, 32, 64));
            if (quad == 0)
                atomicMax(reinterpret_cast<int*>(Mx + col), __float_as_int(mx));
        }
    }
}

// ---------------------------------------------------------------------------
// Kernel 3: grouping + 3-layer MLP + max-pool, one branch per instantiation.
// NG groups per block, WPG waves per group (NG*WPG == 4). f32 in/out,
// bf16 internal (MFMA).
// ---------------------------------------------------------------------------
template <int NS, int C1, int C2, int C3, int NG, int WPG, int CH_OFF>
__global__ __launch_bounds__(256) void mlp_kernel(
    const float* __restrict__ xyz,
    const float* __restrict__ points,
    const float* __restrict__ newxyz,
    const unsigned short* __restrict__ idx,
    const float* __restrict__ w1, const float* __restrict__ b1,
    const float* __restrict__ w2, const float* __restrict__ b2,
    const float* __restrict__ w3, const float* __restrict__ b3,
    float* __restrict__ outfeat) {
    constexpr int SA = 104;            // stride for 96-wide A buffer (+8 pad)
    constexpr int SB = C1 + 8;
    constexpr int SW1 = 104, SW2 = C1 + 8, SW3 = C2 + 8;
    constexpr int NH = (C3 > 64) ? 2 : 1;   // split layer-3 N to cap LDS
    constexpr int C3P = C3 / NH;
    constexpr int WSZ = cmax2(cmax2(C1 * SW1, C2 * SW2), C3P * SW3);
    constexpr int MW = NS / WPG;

    __shared__ __align__(16) unsigned short Abuf[NG][NS][SA];
    __shared__ __align__(16) unsigned short Bbuf[NG][NS][SB];
    __shared__ __align__(16) unsigned short Wbuf[WSZ];
    __shared__ float bbuf[128];
    __shared__ float Mx[NG][C3];
    __shared__ unsigned short idxbuf[NG][NS];

    const int tid = threadIdx.x;
    const int lane = tid & 63;
    const int wave = tid >> 6;
    const int gl = wave / WPG;
    const int mslice = wave % WPG;

    for (int e = tid; e < NG * NS; e += 256)
        (&idxbuf[0][0])[e] = idx[(size_t)blockIdx.x * (NG * NS) + e];
    for (int e = tid; e < NG * C3; e += 256) (&Mx[0][0])[e] = 0.0f;
    load_weights_part<67, 96, C1, SW1>(w1, b1, Wbuf, bbuf, tid, 0, C1);
    __syncthreads();

    // gather: 4 threads per row (16 channels each); q==3 adds g_xyz + zero pad
    for (int rr = tid >> 2; rr < NG * NS; rr += 64) {
        const int q = tid & 3;
        const int g = rr / NS, kk = rr % NS;
        const int gg = blockIdx.x * NG + g;
        const int bb = gg >> 10;
        const int id = idxbuf[g][kk] & 4095;
        const float4* s4 = reinterpret_cast<const float4*>(
            points + (((size_t)bb * 4096 + id) << 6) + q * 16);
        const float4 c0 = s4[0], c1 = s4[1], c2 = s4[2], c3 = s4[3];
        union { uint4 o[2]; unsigned short h[16]; } t16;
        const float cc[16] = {c0.x, c0.y, c0.z, c0.w, c1.x, c1.y, c1.z, c1.w,
                              c2.x, c2.y, c2.z, c2.w, c3.x, c3.y, c3.z, c3.w};
#pragma unroll
        for (int i = 0; i < 16; ++i) t16.h[i] = f2bf(cc[i]);
        *reinterpret_cast<uint4*>(&Abuf[g][kk][q * 16]) = t16.o[0];
        *reinterpret_cast<uint4*>(&Abuf[g][kk][q * 16 + 8]) = t16.o[1];
        if (q == 3) {
            const float* pz = xyz + ((size_t)bb * 4096 + id) * 3;
            const float* nc = newxyz + (size_t)gg * 3;
            Abuf[g][kk][64] = f2bf(pz[0] - nc[0]);
            Abuf[g][kk][65] = f2bf(pz[1] - nc[1]);
            Abuf[g][kk][66] = f2bf(pz[2] - nc[2]);
#pragma unroll
            for (int c = 67; c < 72; ++c) Abuf[g][kk][c] = 0;
            *reinterpret_cast<uint4*>(&Abuf[g][kk][72]) = (uint4){0, 0, 0, 0};
            *reinterpret_cast<uint4*>(&Abuf[g][kk][80]) = (uint4){0, 0, 0, 0};
            *reinterpret_cast<uint4*>(&Abuf[g][kk][88]) = (uint4){0, 0, 0, 0};
        }
    }
    __syncthreads();

    // layer 1: 96(67) -> C1
    layer_mfma<MW, 96, C1, SA, SW1, SB, false>(&Abuf[gl][0][0], &Bbuf[gl][0][0],
                                               Wbuf, bbuf, nullptr, lane, mslice);
    __syncthreads();
    load_weights_part<C1, C1, C2, SW2>(w2, b2, Wbuf, bbuf, tid, 0, C2);
    __syncthreads();
    // layer 2: C1 -> C2
    layer_mfma<MW, C1, C2, SB, SW2, SA, false>(&Bbuf[gl][0][0], &Abuf[gl][0][0],
                                               Wbuf, bbuf, nullptr, lane, mslice);
    __syncthreads();
    // layer 3: C2 -> C3 (in NH halves), fused bias+relu+max
    for (int h = 0; h < NH; ++h) {
        load_weights_part<C2, C2, C3P, SW3>(w3, b3, Wbuf, bbuf, tid, h * C3P, C3);
        __syncthreads();
        layer_mfma<MW, C2, C3P, SA, SW3, 0, true>(&Abuf[gl][0][0], nullptr,
                                                  Wbuf, bbuf, &Mx[gl][0] + h * C3P,
                                                  lane, mslice);
        __syncthreads();
    }

    for (int e = tid; e < NG * C3; e += 256) {
        const int g = e / C3, c = e % C3;
        const size_t gg = (size_t)blockIdx.x * NG + g;
        outfeat[gg * 320 + CH_OFF + c] = (&Mx[0][0])[e];
    }
}

// ---------------------------------------------------------------------------
extern "C" void kernel_launch(void* const* d_in, const int* in_sizes, int n_in,
                              void* d_out, int out_size, void* d_ws, size_t ws_size,
                              hipStream_t stream) {
    (void)in_sizes; (void)n_in; (void)out_size; (void)ws_size;
    const float* xyz = (const float*)d_in[0];
    const float* points = (const float*)d_in[1];
    const float* W[3][3];
    const float* Bi[3][3];
    int p = 2;
    for (int bi = 0; bi < 3; ++bi)
        for (int li = 0; li < 3; ++li) {
            W[bi][li] = (const float*)d_in[p++];
            Bi[bi][li] = (const float*)d_in[p++];
        }
    float* newxyz = (float*)d_out;                  // 8*1024*3
    float* outfeat = (float*)d_out + 8 * 1024 * 3;  // 8*1024*320

    unsigned short* wsu = (unsigned short*)d_ws;    // 2.9 MB total (u16 indices)
    unsigned short* idx0 = wsu;                        // 8192*16
    unsigned short* idx1 = wsu + (size_t)8192 * 16;    // 8192*32
    unsigned short* idx2 = wsu + (size_t)8192 * 48;    // 8192*128

    fps_kernel<<<dim3(8), dim3(1024), 0, stream>>>(xyz, newxyz);
    ballq_kernel<<<dim3(2048), dim3(256), 0, stream>>>(xyz, newxyz, idx0, idx1, idx2);
    mlp_kernel<16, 32, 32, 64, 4, 1, 0><<<dim3(2048), dim3(256), 0, stream>>>(
        xyz, points, newxyz, idx0,
        W[0][0], Bi[0][0], W[0][1], Bi[0][1], W[0][2], Bi[0][2], outfeat);
    mlp_kernel<32, 64, 64, 128, 4, 1, 64><<<dim3(2048), dim3(256), 0, stream>>>(
        xyz, points, newxyz, idx1,
        W[1][0], Bi[1][0], W[1][1], Bi[1][1], W[1][2], Bi[1][2], outfeat);
    mlp_kernel<128, 64, 96, 128, 1, 4, 192><<<dim3(8192), dim3(256), 0, stream>>>(
        xyz, points, newxyz, idx2,
        W[2][0], Bi[2][0], W[2][1], Bi[2][1], W[2][2], Bi[2][2], outfeat);
}

// Round 6
// 1156.095 us; speedup vs baseline: 1.3411x; 1.3411x over previous
//
#include <hip/hip_runtime.h>
#include <stdint.h>

typedef unsigned long long u64;
typedef __attribute__((ext_vector_type(8))) short bf16x8;   // 8 bf16 = 4 VGPRs
typedef __attribute__((ext_vector_type(4))) float f32x4;

__device__ __forceinline__ unsigned short f2bf(float f) {
    unsigned x = __float_as_uint(f);
    unsigned r = (x + 0x7fffu + ((x >> 16) & 1u)) >> 16;   // RNE
    return (unsigned short)r;
}
__device__ __forceinline__ constexpr int cmax2(int a, int b) { return a > b ? a : b; }

// Wave64 max-reduce of a non-negative f32 at VALU speed (DPP, no LDS hops).
__device__ __forceinline__ float wave_max_dpp(float v) {
#define DPP_MAX_STEP(ctrl)                                                     \
    v = fmaxf(v, __int_as_float(__builtin_amdgcn_update_dpp(                   \
               0, __float_as_int(v), (ctrl), 0xf, 0xf, true)))
    DPP_MAX_STEP(0xB1);   // quad_perm xor1
    DPP_MAX_STEP(0x4E);   // quad_perm xor2
    DPP_MAX_STEP(0x141);  // row_half_mirror xor4
    DPP_MAX_STEP(0x140);  // row_mirror xor8
    DPP_MAX_STEP(0x142);  // row_bcast15
    DPP_MAX_STEP(0x143);  // row_bcast31
#undef DPP_MAX_STEP
    return __int_as_float(__builtin_amdgcn_readlane(__float_as_int(v), 63));
}

// ---------------------------------------------------------------------------
// Kernel 1: farthest point sampling (f32 I/O). One block per batch.
// 256 threads = 4 waves (1/SIMD: issue-optimal, R5 post-mortem), 16 pts/thread
// in registers; no coord LDS table. Winner coords travel with the slot.
// Bit-exact vs numpy: ((dx*dx+dy*dy)+dz*dz), fminf chain, argmax-first-tie.
// ---------------------------------------------------------------------------
__global__ __launch_bounds__(256) void fps_kernel(const float* __restrict__ xyz,
                                                  float* __restrict__ newxyz) {
    const int b = blockIdx.x;
    const int t = threadIdx.x;
    const int lane = t & 63;
    const int wave = t >> 6;
    __shared__ __align__(16) u64 skey[2][4];
    __shared__ __align__(16) float scx[2][4], scy[2][4], scz[2][4];

    float px[16], py[16], pz[16], dist[16];
    {
        union { float4 v[12]; float f[48]; } u;
        const float4* src =
            reinterpret_cast<const float4*>(xyz + (size_t)b * 12288) + t * 12;
#pragma unroll
        for (int w = 0; w < 12; ++w) u.v[w] = src[w];
#pragma unroll
        for (int i = 0; i < 16; ++i) {
            px[i] = u.f[3 * i + 0];
            py[i] = u.f[3 * i + 1];
            pz[i] = u.f[3 * i + 2];
            dist[i] = 1e10f;
        }
    }
    // first centroid = point 0 (uniform broadcast load, L2-cached)
    const float* p0 = xyz + (size_t)b * 12288;
    float cx = p0[0], cy = p0[1], cz = p0[2];

    for (int k = 0; k < 1024; ++k) {
        if (t == 0) {
            const size_t o = ((size_t)b * 1024 + k) * 3;
            newxyz[o + 0] = cx; newxyz[o + 1] = cy; newxyz[o + 2] = cz;
        }
#pragma unroll
        for (int i = 0; i < 16; ++i) {
            const float dx = px[i] - cx, dy = py[i] - cy, dz = pz[i] - cz;
            const float d = __fadd_rn(__fadd_rn(__fmul_rn(dx, dx), __fmul_rn(dy, dy)),
                                      __fmul_rn(dz, dz));
            dist[i] = fminf(dist[i], d);
        }
        // thread-local max tree, then ascending-tie scan selecting idx+coords
        float m8[8], m4[4], bv;
#pragma unroll
        for (int i = 0; i < 8; ++i) m8[i] = fmaxf(dist[i], dist[i + 8]);
#pragma unroll
        for (int i = 0; i < 4; ++i) m4[i] = fmaxf(m8[i], m8[i + 4]);
        bv = fmaxf(fmaxf(m4[0], m4[1]), fmaxf(m4[2], m4[3]));
        int bj = 15;
        float bx = px[15], by = py[15], bz = pz[15];
#pragma unroll
        for (int i = 14; i >= 0; --i) {
            const bool e = (dist[i] == bv);
            bj = e ? i : bj;
            bx = e ? px[i] : bx;
            by = e ? py[i] : by;
            bz = e ? pz[i] : bz;
        }
        const int myidx = t * 16 + bj;

        // wave-level: DPP max; first matching lane = smallest global idx
        const float wmax = wave_max_dpp(bv);
        const u64 mask = __ballot(bv == wmax);
        const int fl = (int)__builtin_ctzll(mask);
        const int widx = __builtin_amdgcn_readlane(myidx, fl);
        const int wxi = __builtin_amdgcn_readlane(__float_as_int(bx), fl);
        const int wyi = __builtin_amdgcn_readlane(__float_as_int(by), fl);
        const int wzi = __builtin_amdgcn_readlane(__float_as_int(bz), fl);

        const int p = k & 1;
        if (lane == 0) {
            skey[p][wave] =
                ((u64)__float_as_uint(wmax) << 32) | (unsigned)(4095 - widx);
            scx[p][wave] = __int_as_float(wxi);
            scy[p][wave] = __int_as_float(wyi);
            scz[p][wave] = __int_as_float(wzi);
        }
        __syncthreads();
        // one pipelined LDS hop: 4 keys + 4x3 coords, then 2-level tournament
        const ulonglong2 ka = *reinterpret_cast<const ulonglong2*>(&skey[p][0]);
        const ulonglong2 kb = *reinterpret_cast<const ulonglong2*>(&skey[p][2]);
        const float4 vx = *reinterpret_cast<const float4*>(&scx[p][0]);
        const float4 vy = *reinterpret_cast<const float4*>(&scy[p][0]);
        const float4 vz = *reinterpret_cast<const float4*>(&scz[p][0]);
        const bool g0 = kb.x > ka.x;   // wave2 vs wave0
        const bool g1 = kb.y > ka.y;   // wave3 vs wave1
        const u64 m0 = g0 ? kb.x : ka.x;
        const u64 m1 = g1 ? kb.y : ka.y;
        const float x0 = g0 ? vx.z : vx.x, y0 = g0 ? vy.z : vy.x, z0 = g0 ? vz.z : vz.x;
        const float x1 = g1 ? vx.w : vx.y, y1 = g1 ? vy.w : vy.y, z1 = g1 ? vz.w : vz.y;
        const bool gf = m1 > m0;
        cx = gf ? x1 : x0;
        cy = gf ? y1 : y0;
        cz = gf ? z1 : z0;
    }
}

// ---------------------------------------------------------------------------
// Kernel 2: ball query, all 3 radii in one pass (f32 in, u16 idx out).
// One wave per (b,s). Bit-exact predicate vs numpy (radius^2 folds to f32).
// ---------------------------------------------------------------------------
__global__ __launch_bounds__(256) void ballq_kernel(const float* __restrict__ xyz,
                                                    const float* __restrict__ newxyz,
                                                    unsigned short* __restrict__ idx0,
                                                    unsigned short* __restrict__ idx1,
                                                    unsigned short* __restrict__ idx2) {
    const int wave = threadIdx.x >> 6;
    const int lane = threadIdx.x & 63;
    const int g = blockIdx.x * 4 + wave;   // g = b*1024 + s
    const int b = g >> 10;

    const float* nc = newxyz + (size_t)g * 3;
    const float cx = nc[0], cy = nc[1], cz = nc[2];

    int cnt0 = 0, cnt1 = 0, cnt2 = 0;
    int f0 = 0, f1 = 0, f2 = 0;
    unsigned short* o0 = idx0 + (size_t)g * 16;
    unsigned short* o1 = idx1 + (size_t)g * 32;
    unsigned short* o2 = idx2 + (size_t)g * 128;
    const float* base = xyz + (size_t)b * 12288;

    for (int it = 0; it < 64; ++it) {
        const int j = it * 64 + lane;
        const float* p = base + j * 3;
        const float dx = p[0] - cx;
        const float dy = p[1] - cy;
        const float dz = p[2] - cz;
        const float d2 = __fadd_rn(__fadd_rn(__fmul_rn(dx, dx), __fmul_rn(dy, dy)),
                                   __fmul_rn(dz, dz));
        const bool p0 = d2 < 0.01f;   // f32(0.1*0.1)
        const bool p1 = d2 < 0.04f;   // f32(0.2*0.2)
        const bool p2 = d2 < 0.16f;   // f32(0.4*0.4)
        const u64 m0 = __ballot(p0);
        const u64 m1 = __ballot(p1);
        const u64 m2 = __ballot(p2);
        const u64 lower = (((u64)1) << lane) - 1;

        if (cnt0 < 16) {
            if (cnt0 == 0 && m0) f0 = it * 64 + __builtin_ctzll(m0);
            const int pos = cnt0 + (int)__builtin_popcountll(m0 & lower);
            if (p0 && pos < 16) o0[pos] = (unsigned short)j;
            cnt0 += (int)__builtin_popcountll(m0);
        }
        if (cnt1 < 32) {
            if (cnt1 == 0 && m1) f1 = it * 64 + __builtin_ctzll(m1);
            const int pos = cnt1 + (int)__builtin_popcountll(m1 & lower);
            if (p1 && pos < 32) o1[pos] = (unsigned short)j;
            cnt1 += (int)__builtin_popcountll(m1);
        }
        if (cnt2 < 128) {
            if (cnt2 == 0 && m2) f2 = it * 64 + __builtin_ctzll(m2);
            const int pos = cnt2 + (int)__builtin_popcountll(m2 & lower);
            if (p2 && pos < 128) o2[pos] = (unsigned short)j;
            cnt2 += (int)__builtin_popcountll(m2);
        }
        if (cnt0 >= 16 && cnt1 >= 32 && cnt2 >= 128) break;
    }
    for (int pos = cnt0 + lane; pos < 16; pos += 64) o0[pos] = (unsigned short)f0;
    for (int pos = cnt1 + lane; pos < 32; pos += 64) o1[pos] = (unsigned short)f1;
    for (int pos = cnt2 + lane; pos < 128; pos += 64) o2[pos] = (unsigned short)f2;
}

// ---------------------------------------------------------------------------
// MLP helpers
// ---------------------------------------------------------------------------
template <int Cin, int Kp, int Cout, int SW>
__device__ __forceinline__ void load_weights_part(const float* __restrict__ w,
                                                  const float* __restrict__ bias,
                                                  unsigned short* Wbuf, float* bbuf,
                                                  int tid, int noff, int ld) {
    for (int e = tid; e < Cout * Kp; e += 256) {
        const int n = e % Cout, k = e / Cout;
        Wbuf[n * SW + k] = (k < Cin) ? f2bf(w[k * ld + noff + n]) : (unsigned short)0;
    }
    for (int e = tid; e < Cout; e += 256) bbuf[e] = bias[noff + e];
}

// One wave computes MW rows x Cout cols of one layer.
// A (m89/m120): A[m=lane&15][k=quad*8+j]; B staged transposed [n][k] with
// n=lane&15, k=quad*8+j; C/D: col=lane&15, row=quad*4+reg.
template <int MW, int Kp, int Cout, int SIN, int SW, int SOUT, bool LAST>
__device__ __forceinline__ void layer_mfma(const unsigned short* __restrict__ src,
                                           unsigned short* __restrict__ dst,
                                           const unsigned short* __restrict__ Wbuf,
                                           const float* __restrict__ bbuf,
                                           float* __restrict__ Mx,
                                           int lane, int mslice) {
    constexpr int MT = MW / 16;
    constexpr int NT = Cout / 16;
    const int ml = lane & 15;
    const int quad = lane >> 4;

    f32x4 acc[MT][NT];
#pragma unroll
    for (int mt = 0; mt < MT; ++mt)
#pragma unroll
        for (int nt = 0; nt < NT; ++nt) acc[mt][nt] = (f32x4){0.f, 0.f, 0.f, 0.f};

#pragma unroll
    for (int ks = 0; ks < Kp; ks += 32) {
        bf16x8 afr[MT], bfr[NT];
#pragma unroll
        for (int mt = 0; mt < MT; ++mt)
            afr[mt] = *reinterpret_cast<const bf16x8*>(
                src + (mslice * MW + mt * 16 + ml) * SIN + ks + quad * 8);
#pragma unroll
        for (int nt = 0; nt < NT; ++nt)
            bfr[nt] = *reinterpret_cast<const bf16x8*>(
                Wbuf + (nt * 16 + ml) * SW + ks + quad * 8);
#pragma unroll
        for (int mt = 0; mt < MT; ++mt)
#pragma unroll
            for (int nt = 0; nt < NT; ++nt)
                acc[mt][nt] = __builtin_amdgcn_mfma_f32_16x16x32_bf16(
                    afr[mt], bfr[nt], acc[mt][nt], 0, 0, 0);
    }

#pragma unroll
    for (int nt = 0; nt < NT; ++nt) {
        const int col = nt * 16 + ml;
        const float bv = bbuf[col];
        if constexpr (!LAST) {
#pragma unroll
            for (int mt = 0; mt < MT; ++mt)
#pragma unroll
                for (int r = 0; r < 4; ++r) {
                    const float v = fmaxf(acc[mt][nt][r] + bv, 0.0f);
                    dst[(mslice * MW + mt * 16 + quad * 4 + r) * SOUT + col] = f2bf(v);
                }
        } else {
            float mx = 0.0f;   // relu floor folds into the max
#pragma unroll
            for (int mt = 0; mt < MT; ++mt)
#pragma unroll
                for (int r = 0; r < 4; ++r) mx = fmaxf(mx, acc[mt][nt][r] + bv);
            mx = fmaxf(mx, __shfl_xor(mx, 16, 64));
            mx = fmaxf(mx, __shfl_xor(mx, 32, 64));
            if (quad == 0)
                atomicMax(reinterpret_cast<int*>(Mx + col), __float_as_int(mx));
        }
    }
}

// ---------------------------------------------------------------------------
// Kernel 3: grouping + 3-layer MLP + max-pool, one branch per instantiation.
// NG groups per block, WPG waves per group (NG*WPG == 4). f32 in/out,
// bf16 internal (MFMA).
// ---------------------------------------------------------------------------
template <int NS, int C1, int C2, int C3, int NG, int WPG, int CH_OFF>
__global__ __launch_bounds__(256) void mlp_kernel(
    const float* __restrict__ xyz,
    const float* __restrict__ points,
    const float* __restrict__ newxyz,
    const unsigned short* __restrict__ idx,
    const float* __restrict__ w1, const float* __restrict__ b1,
    const float* __restrict__ w2, const float* __restrict__ b2,
    const float* __restrict__ w3, const float* __restrict__ b3,
    float* __restrict__ outfeat) {
    constexpr int SA = 104;            // stride for 96-wide A buffer (+8 pad)
    constexpr int SB = C1 + 8;
    constexpr int SW1 = 104, SW2 = C1 + 8, SW3 = C2 + 8;
    constexpr int NH = (C3 > 64) ? 2 : 1;   // split layer-3 N to cap LDS
    constexpr int C3P = C3 / NH;
    constexpr int WSZ = cmax2(cmax2(C1 * SW1, C2 * SW2), C3P * SW3);
    constexpr int MW = NS / WPG;

    __shared__ __align__(16) unsigned short Abuf[NG][NS][SA];
    __shared__ __align__(16) unsigned short Bbuf[NG][NS][SB];
    __shared__ __align__(16) unsigned short Wbuf[WSZ];
    __shared__ float bbuf[128];
    __shared__ float Mx[NG][C3];
    __shared__ unsigned short idxbuf[NG][NS];

    const int tid = threadIdx.x;
    const int lane = tid & 63;
    const int wave = tid >> 6;
    const int gl = wave / WPG;
    const int mslice = wave % WPG;

    for (int e = tid; e < NG * NS; e += 256)
        (&idxbuf[0][0])[e] = idx[(size_t)blockIdx.x * (NG * NS) + e];
    for (int e = tid; e < NG * C3; e += 256) (&Mx[0][0])[e] = 0.0f;
    load_weights_part<67, 96, C1, SW1>(w1, b1, Wbuf, bbuf, tid, 0, C1);
    __syncthreads();

    // gather: 4 threads per row (16 channels each); q==3 adds g_xyz + zero pad
    for (int rr = tid >> 2; rr < NG * NS; rr += 64) {
        const int q = tid & 3;
        const int g = rr / NS, kk = rr % NS;
        const int gg = blockIdx.x * NG + g;
        const int bb = gg >> 10;
        const int id = idxbuf[g][kk] & 4095;
        const float4* s4 = reinterpret_cast<const float4*>(
            points + (((size_t)bb * 4096 + id) << 6) + q * 16);
        const float4 c0 = s4[0], c1 = s4[1], c2 = s4[2], c3 = s4[3];
        union { uint4 o[2]; unsigned short h[16]; } t16;
        const float cc[16] = {c0.x, c0.y, c0.z, c0.w, c1.x, c1.y, c1.z, c1.w,
                              c2.x, c2.y, c2.z, c2.w, c3.x, c3.y, c3.z, c3.w};
#pragma unroll
        for (int i = 0; i < 16; ++i) t16.h[i] = f2bf(cc[i]);
        *reinterpret_cast<uint4*>(&Abuf[g][kk][q * 16]) = t16.o[0];
        *reinterpret_cast<uint4*>(&Abuf[g][kk][q * 16 + 8]) = t16.o[1];
        if (q == 3) {
            const float* pz = xyz + ((size_t)bb * 4096 + id) * 3;
            const float* nc = newxyz + (size_t)gg * 3;
            Abuf[g][kk][64] = f2bf(pz[0] - nc[0]);
            Abuf[g][kk][65] = f2bf(pz[1] - nc[1]);
            Abuf[g][kk][66] = f2bf(pz[2] - nc[2]);
#pragma unroll
            for (int c = 67; c < 72; ++c) Abuf[g][kk][c] = 0;
            *reinterpret_cast<uint4*>(&Abuf[g][kk][72]) = (uint4){0, 0, 0, 0};
            *reinterpret_cast<uint4*>(&Abuf[g][kk][80]) = (uint4){0, 0, 0, 0};
            *reinterpret_cast<uint4*>(&Abuf[g][kk][88]) = (uint4){0, 0, 0, 0};
        }
    }
    __syncthreads();

    // layer 1: 96(67) -> C1
    layer_mfma<MW, 96, C1, SA, SW1, SB, false>(&Abuf[gl][0][0], &Bbuf[gl][0][0],
                                               Wbuf, bbuf, nullptr, lane, mslice);
    __syncthreads();
    load_weights_part<C1, C1, C2, SW2>(w2, b2, Wbuf, bbuf, tid, 0, C2);
    __syncthreads();
    // layer 2: C1 -> C2
    layer_mfma<MW, C1, C2, SB, SW2, SA, false>(&Bbuf[gl][0][0], &Abuf[gl][0][0],
                                               Wbuf, bbuf, nullptr, lane, mslice);
    __syncthreads();
    // layer 3: C2 -> C3 (in NH halves), fused bias+relu+max
    for (int h = 0; h < NH; ++h) {
        load_weights_part<C2, C2, C3P, SW3>(w3, b3, Wbuf, bbuf, tid, h * C3P, C3);
        __syncthreads();
        layer_mfma<MW, C2, C3P, SA, SW3, 0, true>(&Abuf[gl][0][0], nullptr,
                                                  Wbuf, bbuf, &Mx[gl][0] + h * C3P,
                                                  lane, mslice);
        __syncthreads();
    }

    for (int e = tid; e < NG * C3; e += 256) {
        const int g = e / C3, c = e % C3;
        const size_t gg = (size_t)blockIdx.x * NG + g;
        outfeat[gg * 320 + CH_OFF + c] = (&Mx[0][0])[e];
    }
}

// ---------------------------------------------------------------------------
extern "C" void kernel_launch(void* const* d_in, const int* in_sizes, int n_in,
                              void* d_out, int out_size, void* d_ws, size_t ws_size,
                              hipStream_t stream) {
    (void)in_sizes; (void)n_in; (void)out_size; (void)ws_size;
    const float* xyz = (const float*)d_in[0];
    const float* points = (const float*)d_in[1];
    const float* W[3][3];
    const float* Bi[3][3];
    int p = 2;
    for (int bi = 0; bi < 3; ++bi)
        for (int li = 0; li < 3; ++li) {
            W[bi][li] = (const float*)d_in[p++];
            Bi[bi][li] = (const float*)d_in[p++];
        }
    float* newxyz = (float*)d_out;                  // 8*1024*3
    float* outfeat = (float*)d_out + 8 * 1024 * 3;  // 8*1024*320

    unsigned short* wsu = (unsigned short*)d_ws;    // 2.9 MB total (u16 indices)
    unsigned short* idx0 = wsu;                        // 8192*16
    unsigned short* idx1 = wsu + (size_t)8192 * 16;    // 8192*32
    unsigned short* idx2 = wsu + (size_t)8192 * 48;    // 8192*128

    fps_kernel<<<dim3(8), dim3(256), 0, stream>>>(xyz, newxyz);
    ballq_kernel<<<dim3(2048), dim3(256), 0, stream>>>(xyz, newxyz, idx0, idx1, idx2);
    mlp_kernel<16, 32, 32, 64, 4, 1, 0><<<dim3(2048), dim3(256), 0, stream>>>(
        xyz, points, newxyz, idx0,
        W[0][0], Bi[0][0], W[0][1], Bi[0][1], W[0][2], Bi[0][2], outfeat);
    mlp_kernel<32, 64, 64, 128, 4, 1, 64><<<dim3(2048), dim3(256), 0, stream>>>(
        xyz, points, newxyz, idx1,
        W[1][0], Bi[1][0], W[1][1], Bi[1][1], W[1][2], Bi[1][2], outfeat);
    mlp_kernel<128, 64, 96, 128, 1, 4, 192><<<dim3(8192), dim3(256), 0, stream>>>(
        xyz, points, newxyz, idx2,
        W[2][0], Bi[2][0], W[2][1], Bi[2][1], W[2][2], Bi[2][2], outfeat);
}

// Round 7
// 980.403 us; speedup vs baseline: 1.5815x; 1.1792x over previous
//
#include <hip/hip_runtime.h>
#include <stdint.h>

typedef unsigned long long u64;
typedef __attribute__((ext_vector_type(8))) short bf16x8;   // 8 bf16 = 4 VGPRs
typedef __attribute__((ext_vector_type(4))) float f32x4;
typedef __attribute__((ext_vector_type(2))) float f32x2;    // v_pk_*_f32 pair

__device__ __forceinline__ unsigned short f2bf(float f) {
    unsigned x = __float_as_uint(f);
    unsigned r = (x + 0x7fffu + ((x >> 16) & 1u)) >> 16;   // RNE
    return (unsigned short)r;
}
__device__ __forceinline__ constexpr int cmax2(int a, int b) { return a > b ? a : b; }

// Wave64 max-reduce of a non-negative f32 at VALU speed (DPP, no LDS hops).
__device__ __forceinline__ float wave_max_dpp(float v) {
#define DPP_MAX_STEP(ctrl)                                                     \
    v = fmaxf(v, __int_as_float(__builtin_amdgcn_update_dpp(                   \
               0, __float_as_int(v), (ctrl), 0xf, 0xf, true)))
    DPP_MAX_STEP(0xB1);   // quad_perm xor1
    DPP_MAX_STEP(0x4E);   // quad_perm xor2
    DPP_MAX_STEP(0x141);  // row_half_mirror xor4
    DPP_MAX_STEP(0x140);  // row_mirror xor8
    DPP_MAX_STEP(0x142);  // row_bcast15
    DPP_MAX_STEP(0x143);  // row_bcast31
#undef DPP_MAX_STEP
    return __int_as_float(__builtin_amdgcn_readlane(__float_as_int(v), 63));
}

// ---------------------------------------------------------------------------
// Kernel 1: farthest point sampling (f32 I/O). One block per batch.
// R4 skeleton (coord LDS table + u64-key reduction — fastest measured) with
// the distance update packed into v_pk_{add,mul}_f32 (f32x2 pairs, contract
// off => per-component IEEE-RN, bit-exact vs numpy ((dx^2+dy^2)+dz^2)).
// 256 threads = 4 waves (1/SIMD: issue-optimal, R5 post-mortem).
// ---------------------------------------------------------------------------
__global__ __launch_bounds__(256) void fps_kernel(const float* __restrict__ xyz,
                                                  float* __restrict__ newxyz) {
#pragma clang fp contract(off)
    const int b = blockIdx.x;
    const int t = threadIdx.x;
    const int lane = t & 63;
    const int wave = t >> 6;
    __shared__ float xs[4096], ys[4096], zs[4096];
    __shared__ __align__(16) u64 skey[2][4];

    f32x2 px[8], py[8], pz[8], dist[8];
    {
        union { float4 v[12]; float f[48]; } u;
        const float4* src =
            reinterpret_cast<const float4*>(xyz + (size_t)b * 12288) + t * 12;
#pragma unroll
        for (int w = 0; w < 12; ++w) u.v[w] = src[w];
#pragma unroll
        for (int i = 0; i < 8; ++i) {
            px[i] = (f32x2){u.f[6 * i + 0], u.f[6 * i + 3]};
            py[i] = (f32x2){u.f[6 * i + 1], u.f[6 * i + 4]};
            pz[i] = (f32x2){u.f[6 * i + 2], u.f[6 * i + 5]};
            dist[i] = (f32x2){1e10f, 1e10f};
            const int j = t * 16 + 2 * i;
            xs[j] = px[i].x; xs[j + 1] = px[i].y;
            ys[j] = py[i].x; ys[j + 1] = py[i].y;
            zs[j] = pz[i].x; zs[j + 1] = pz[i].y;
        }
    }
    __syncthreads();

    int far = 0;
    for (int k = 0; k < 1024; ++k) {
        const float cx = xs[far], cy = ys[far], cz = zs[far];
        if (t == 0) {
            const size_t o = ((size_t)b * 1024 + k) * 3;
            newxyz[o + 0] = cx; newxyz[o + 1] = cy; newxyz[o + 2] = cz;
        }
        const f32x2 c2x = (f32x2){cx, cx};
        const f32x2 c2y = (f32x2){cy, cy};
        const f32x2 c2z = (f32x2){cz, cz};
#pragma unroll
        for (int i = 0; i < 8; ++i) {
            const f32x2 dx = px[i] - c2x;
            const f32x2 dy = py[i] - c2y;
            const f32x2 dz = pz[i] - c2z;
            const f32x2 s = dx * dx + dy * dy;   // pk_mul + pk_add (no fma)
            const f32x2 d = s + dz * dz;
            dist[i].x = fminf(dist[i].x, d.x);
            dist[i].y = fminf(dist[i].y, d.y);
        }
        // thread-local max tree over the 16 scalars, then ascending-tie scan
        float dv[16];
#pragma unroll
        for (int i = 0; i < 8; ++i) { dv[2 * i] = dist[i].x; dv[2 * i + 1] = dist[i].y; }
        float m8[8], m4[4], bv;
#pragma unroll
        for (int i = 0; i < 8; ++i) m8[i] = fmaxf(dv[i], dv[i + 8]);
#pragma unroll
        for (int i = 0; i < 4; ++i) m4[i] = fmaxf(m8[i], m8[i + 4]);
        bv = fmaxf(fmaxf(m4[0], m4[1]), fmaxf(m4[2], m4[3]));
        int bj = 15;
#pragma unroll
        for (int i = 14; i >= 0; --i) bj = (dv[i] == bv) ? i : bj;
        const int myidx = t * 16 + bj;

        // wave-level: DPP max; first matching lane = smallest global idx
        const float wmax = wave_max_dpp(bv);
        const u64 mask = __ballot(bv == wmax);
        const int fl = (int)__builtin_ctzll(mask);
        const int widx = __builtin_amdgcn_readlane(myidx, fl);

        const int p = k & 1;
        if (lane == 0)
            skey[p][wave] =
                ((u64)__float_as_uint(wmax) << 32) | (unsigned)(4095 - widx);
        __syncthreads();
        const ulonglong2 ka = *reinterpret_cast<const ulonglong2*>(&skey[p][0]);
        const ulonglong2 kb = *reinterpret_cast<const ulonglong2*>(&skey[p][2]);
        const u64 m01 = (ka.x > ka.y) ? ka.x : ka.y;
        const u64 m23 = (kb.x > kb.y) ? kb.x : kb.y;
        const u64 mm = (m01 > m23) ? m01 : m23;
        far = 4095 - (int)(unsigned)(mm & 0xffffffffull);
    }
}

// ---------------------------------------------------------------------------
// Kernel 2: ball query, all 3 radii in one pass (f32 in, u16 idx out).
// One wave per (b,s). Bit-exact predicate vs numpy (radius^2 folds to f32).
// ---------------------------------------------------------------------------
__global__ __launch_bounds__(256) void ballq_kernel(const float* __restrict__ xyz,
                                                    const float* __restrict__ newxyz,
                                                    unsigned short* __restrict__ idx0,
                                                    unsigned short* __restrict__ idx1,
                                                    unsigned short* __restrict__ idx2) {
    const int wave = threadIdx.x >> 6;
    const int lane = threadIdx.x & 63;
    const int g = blockIdx.x * 4 + wave;   // g = b*1024 + s
    const int b = g >> 10;

    const float* nc = newxyz + (size_t)g * 3;
    const float cx = nc[0], cy = nc[1], cz = nc[2];

    int cnt0 = 0, cnt1 = 0, cnt2 = 0;
    int f0 = 0, f1 = 0, f2 = 0;
    unsigned short* o0 = idx0 + (size_t)g * 16;
    unsigned short* o1 = idx1 + (size_t)g * 32;
    unsigned short* o2 = idx2 + (size_t)g * 128;
    const float* base = xyz + (size_t)b * 12288;

    for (int it = 0; it < 64; ++it) {
        const int j = it * 64 + lane;
        const float* p = base + j * 3;
        const float dx = p[0] - cx;
        const float dy = p[1] - cy;
        const float dz = p[2] - cz;
        const float d2 = __fadd_rn(__fadd_rn(__fmul_rn(dx, dx), __fmul_rn(dy, dy)),
                                   __fmul_rn(dz, dz));
        const bool p0 = d2 < 0.01f;   // f32(0.1*0.1)
        const bool p1 = d2 < 0.04f;   // f32(0.2*0.2)
        const bool p2 = d2 < 0.16f;   // f32(0.4*0.4)
        const u64 m0 = __ballot(p0);
        const u64 m1 = __ballot(p1);
        const u64 m2 = __ballot(p2);
        const u64 lower = (((u64)1) << lane) - 1;

        if (cnt0 < 16) {
            if (cnt0 == 0 && m0) f0 = it * 64 + __builtin_ctzll(m0);
            const int pos = cnt0 + (int)__builtin_popcountll(m0 & lower);
            if (p0 && pos < 16) o0[pos] = (unsigned short)j;
            cnt0 += (int)__builtin_popcountll(m0);
        }
        if (cnt1 < 32) {
            if (cnt1 == 0 && m1) f1 = it * 64 + __builtin_ctzll(m1);
            const int pos = cnt1 + (int)__builtin_popcountll(m1 & lower);
            if (p1 && pos < 32) o1[pos] = (unsigned short)j;
            cnt1 += (int)__builtin_popcountll(m1);
        }
        if (cnt2 < 128) {
            if (cnt2 == 0 && m2) f2 = it * 64 + __builtin_ctzll(m2);
            const int pos = cnt2 + (int)__builtin_popcountll(m2 & lower);
            if (p2 && pos < 128) o2[pos] = (unsigned short)j;
            cnt2 += (int)__builtin_popcountll(m2);
        }
        if (cnt0 >= 16 && cnt1 >= 32 && cnt2 >= 128) break;
    }
    for (int pos = cnt0 + lane; pos < 16; pos += 64) o0[pos] = (unsigned short)f0;
    for (int pos = cnt1 + lane; pos < 32; pos += 64) o1[pos] = (unsigned short)f1;
    for (int pos = cnt2 + lane; pos < 128; pos += 64) o2[pos] = (unsigned short)f2;
}

// ---------------------------------------------------------------------------
// MLP helpers
// ---------------------------------------------------------------------------
template <int Cin, int Kp, int Cout, int SW>
__device__ __forceinline__ void load_weights_part(const float* __restrict__ w,
                                                  const float* __restrict__ bias,
                                                  unsigned short* Wbuf, float* bbuf,
                                                  int tid, int noff, int ld) {
    for (int e = tid; e < Cout * Kp; e += 256) {
        const int n = e % Cout, k = e / Cout;
        Wbuf[n * SW + k] = (k < Cin) ? f2bf(w[k * ld + noff + n]) : (unsigned short)0;
    }
    for (int e = tid; e < Cout; e += 256) bbuf[e] = bias[noff + e];
}

// One wave computes MW rows x Cout cols of one layer.
// A (m89/m120): A[m=lane&15][k=quad*8+j]; B staged transposed [n][k] with
// n=lane&15, k=quad*8+j; C/D: col=lane&15, row=quad*4+reg.
template <int MW, int Kp, int Cout, int SIN, int SW, int SOUT, bool LAST>
__device__ __forceinline__ void layer_mfma(const unsigned short* __restrict__ src,
                                           unsigned short* __restrict__ dst,
                                           const unsigned short* __restrict__ Wbuf,
                                           const float* __restrict__ bbuf,
                                           float* __restrict__ Mx,
                                           int lane, int mslice) {
    constexpr int MT = MW / 16;
    constexpr int NT = Cout / 16;
    const int ml = lane & 15;
    const int quad = lane >> 4;

    f32x4 acc[MT][NT];
#pragma unroll
    for (int mt = 0; mt < MT; ++mt)
#pragma unroll
        for (int nt = 0; nt < NT; ++nt) acc[mt][nt] = (f32x4){0.f, 0.f, 0.f, 0.f};

#pragma unroll
    for (int ks = 0; ks < Kp; ks += 32) {
        bf16x8 afr[MT], bfr[NT];
#pragma unroll
        for (int mt = 0; mt < MT; ++mt)
            afr[mt] = *reinterpret_cast<const bf16x8*>(
                src + (mslice * MW + mt * 16 + ml) * SIN + ks + quad * 8);
#pragma unroll
        for (int nt = 0; nt < NT; ++nt)
            bfr[nt] = *reinterpret_cast<const bf16x8*>(
                Wbuf + (nt * 16 + ml) * SW + ks + quad * 8);
#pragma unroll
        for (int mt = 0; mt < MT; ++mt)
#pragma unroll
            for (int nt = 0; nt < NT; ++nt)
                acc[mt][nt] = __builtin_amdgcn_mfma_f32_16x16x32_bf16(
                    afr[mt], bfr[nt], acc[mt][nt], 0, 0, 0);
    }

#pragma unroll
    for (int nt = 0; nt < NT; ++nt) {
        const int col = nt * 16 + ml;
        const float bv = bbuf[col];
        if constexpr (!LAST) {
#pragma unroll
            for (int mt = 0; mt < MT; ++mt)
#pragma unroll
                for (int r = 0; r < 4; ++r) {
                    const float v = fmaxf(acc[mt][nt][r] + bv, 0.0f);
                    dst[(mslice * MW + mt * 16 + quad * 4 + r) * SOUT + col] = f2bf(v);
                }
        } else {
            float mx = 0.0f;   // relu floor folds into the max
#pragma unroll
            for (int mt = 0; mt < MT; ++mt)
#pragma unroll
                for (int r = 0; r < 4; ++r) mx = fmaxf(mx, acc[mt][nt][r] + bv);
            mx = fmaxf(mx, __shfl_xor(mx, 16, 64));
            mx = fmaxf(mx, __shfl_xor(mx, 32, 64));
            if (quad == 0)
                atomicMax(reinterpret_cast<int*>(Mx + col), __float_as_int(mx));
        }
    }
}

// ---------------------------------------------------------------------------
// Kernel 3: grouping + 3-layer MLP + max-pool, one branch per instantiation.
// NG groups per block, WPG waves per group (NG*WPG == 4). f32 in/out,
// bf16 internal (MFMA).
// ---------------------------------------------------------------------------
template <int NS, int C1, int C2, int C3, int NG, int WPG, int CH_OFF>
__global__ __launch_bounds__(256) void mlp_kernel(
    const float* __restrict__ xyz,
    const float* __restrict__ points,
    const float* __restrict__ newxyz,
    const unsigned short* __restrict__ idx,
    const float* __restrict__ w1, const float* __restrict__ b1,
    const float* __restrict__ w2, const float* __restrict__ b2,
    const float* __restrict__ w3, const float* __restrict__ b3,
    float* __restrict__ outfeat) {
    constexpr int SA = 104;            // stride for 96-wide A buffer (+8 pad)
    constexpr int SB = C1 + 8;
    constexpr int SW1 = 104, SW2 = C1 + 8, SW3 = C2 + 8;
    constexpr int NH = (C3 > 64) ? 2 : 1;   // split layer-3 N to cap LDS
    constexpr int C3P = C3 / NH;
    constexpr int WSZ = cmax2(cmax2(C1 * SW1, C2 * SW2), C3P * SW3);
    constexpr int MW = NS / WPG;

    __shared__ __align__(16) unsigned short Abuf[NG][NS][SA];
    __shared__ __align__(16) unsigned short Bbuf[NG][NS][SB];
    __shared__ __align__(16) unsigned short Wbuf[WSZ];
    __shared__ float bbuf[128];
    __shared__ float Mx[NG][C3];
    __shared__ unsigned short idxbuf[NG][NS];

    const int tid = threadIdx.x;
    const int lane = tid & 63;
    const int wave = tid >> 6;
    const int gl = wave / WPG;
    const int mslice = wave % WPG;

    for (int e = tid; e < NG * NS; e += 256)
        (&idxbuf[0][0])[e] = idx[(size_t)blockIdx.x * (NG * NS) + e];
    for (int e = tid; e < NG * C3; e += 256) (&Mx[0][0])[e] = 0.0f;
    load_weights_part<67, 96, C1, SW1>(w1, b1, Wbuf, bbuf, tid, 0, C1);
    __syncthreads();

    // gather: 4 threads per row (16 channels each); q==3 adds g_xyz + zero pad
    for (int rr = tid >> 2; rr < NG * NS; rr += 64) {
        const int q = tid & 3;
        const int g = rr / NS, kk = rr % NS;
        const int gg = blockIdx.x * NG + g;
        const int bb = gg >> 10;
        const int id = idxbuf[g][kk] & 4095;
        const float4* s4 = reinterpret_cast<const float4*>(
            points + (((size_t)bb * 4096 + id) << 6) + q * 16);
        const float4 c0 = s4[0], c1 = s4[1], c2 = s4[2], c3 = s4[3];
        union { uint4 o[2]; unsigned short h[16]; } t16;
        const float cc[16] = {c0.x, c0.y, c0.z, c0.w, c1.x, c1.y, c1.z, c1.w,
                              c2.x, c2.y, c2.z, c2.w, c3.x, c3.y, c3.z, c3.w};
#pragma unroll
        for (int i = 0; i < 16; ++i) t16.h[i] = f2bf(cc[i]);
        *reinterpret_cast<uint4*>(&Abuf[g][kk][q * 16]) = t16.o[0];
        *reinterpret_cast<uint4*>(&Abuf[g][kk][q * 16 + 8]) = t16.o[1];
        if (q == 3) {
            const float* pz = xyz + ((size_t)bb * 4096 + id) * 3;
            const float* nc = newxyz + (size_t)gg * 3;
            Abuf[g][kk][64] = f2bf(pz[0] - nc[0]);
            Abuf[g][kk][65] = f2bf(pz[1] - nc[1]);
            Abuf[g][kk][66] = f2bf(pz[2] - nc[2]);
#pragma unroll
            for (int c = 67; c < 72; ++c) Abuf[g][kk][c] = 0;
            *reinterpret_cast<uint4*>(&Abuf[g][kk][72]) = (uint4){0, 0, 0, 0};
            *reinterpret_cast<uint4*>(&Abuf[g][kk][80]) = (uint4){0, 0, 0, 0};
            *reinterpret_cast<uint4*>(&Abuf[g][kk][88]) = (uint4){0, 0, 0, 0};
        }
    }
    __syncthreads();

    // layer 1: 96(67) -> C1
    layer_mfma<MW, 96, C1, SA, SW1, SB, false>(&Abuf[gl][0][0], &Bbuf[gl][0][0],
                                               Wbuf, bbuf, nullptr, lane, mslice);
    __syncthreads();
    load_weights_part<C1, C1, C2, SW2>(w2, b2, Wbuf, bbuf, tid, 0, C2);
    __syncthreads();
    // layer 2: C1 -> C2
    layer_mfma<MW, C1, C2, SB, SW2, SA, false>(&Bbuf[gl][0][0], &Abuf[gl][0][0],
                                               Wbuf, bbuf, nullptr, lane, mslice);
    __syncthreads();
    // layer 3: C2 -> C3 (in NH halves), fused bias+relu+max
    for (int h = 0; h < NH; ++h) {
        load_weights_part<C2, C2, C3P, SW3>(w3, b3, Wbuf, bbuf, tid, h * C3P, C3);
        __syncthreads();
        layer_mfma<MW, C2, C3P, SA, SW3, 0, true>(&Abuf[gl][0][0], nullptr,
                                                  Wbuf, bbuf, &Mx[gl][0] + h * C3P,
                                                  lane, mslice);
        __syncthreads();
    }

    for (int e = tid; e < NG * C3; e += 256) {
        const int g = e / C3, c = e % C3;
        const size_t gg = (size_t)blockIdx.x * NG + g;
        outfeat[gg * 320 + CH_OFF + c] = (&Mx[0][0])[e];
    }
}

// ---------------------------------------------------------------------------
extern "C" void kernel_launch(void* const* d_in, const int* in_sizes, int n_in,
                              void* d_out, int out_size, void* d_ws, size_t ws_size,
                              hipStream_t stream) {
    (void)in_sizes; (void)n_in; (void)out_size; (void)ws_size;
    const float* xyz = (const float*)d_in[0];
    const float* points = (const float*)d_in[1];
    const float* W[3][3];
    const float* Bi[3][3];
    int p = 2;
    for (int bi = 0; bi < 3; ++bi)
        for (int li = 0; li < 3; ++li) {
            W[bi][li] = (const float*)d_in[p++];
            Bi[bi][li] = (const float*)d_in[p++];
        }
    float* newxyz = (float*)d_out;                  // 8*1024*3
    float* outfeat = (float*)d_out + 8 * 1024 * 3;  // 8*1024*320

    unsigned short* wsu = (unsigned short*)d_ws;    // 2.9 MB total (u16 indices)
    unsigned short* idx0 = wsu;                        // 8192*16
    unsigned short* idx1 = wsu + (size_t)8192 * 16;    // 8192*32
    unsigned short* idx2 = wsu + (size_t)8192 * 48;    // 8192*128

    fps_kernel<<<dim3(8), dim3(256), 0, stream>>>(xyz, newxyz);
    ballq_kernel<<<dim3(2048), dim3(256), 0, stream>>>(xyz, newxyz, idx0, idx1, idx2);
    mlp_kernel<16, 32, 32, 64, 4, 1, 0><<<dim3(2048), dim3(256), 0, stream>>>(
        xyz, points, newxyz, idx0,
        W[0][0], Bi[0][0], W[0][1], Bi[0][1], W[0][2], Bi[0][2], outfeat);
    mlp_kernel<32, 64, 64, 128, 4, 1, 64><<<dim3(2048), dim3(256), 0, stream>>>(
        xyz, points, newxyz, idx1,
        W[1][0], Bi[1][0], W[1][1], Bi[1][1], W[1][2], Bi[1][2], outfeat);
    mlp_kernel<128, 64, 96, 128, 1, 4, 192><<<dim3(8192), dim3(256), 0, stream>>>(
        xyz, points, newxyz, idx2,
        W[2][0], Bi[2][0], W[2][1], Bi[2][1], W[2][2], Bi[2][2], outfeat);
}

// Round 8
// 887.431 us; speedup vs baseline: 1.7472x; 1.1048x over previous
//
#include <hip/hip_runtime.h>
#include <stdint.h>

typedef unsigned long long u64;
typedef __attribute__((ext_vector_type(8))) short bf16x8;   // 8 bf16 = 4 VGPRs
typedef __attribute__((ext_vector_type(4))) float f32x4;
typedef __attribute__((ext_vector_type(2))) float f32x2;    // v_pk_*_f32 pair

__device__ __forceinline__ unsigned short f2bf(float f) {
    unsigned x = __float_as_uint(f);
    unsigned r = (x + 0x7fffu + ((x >> 16) & 1u)) >> 16;   // RNE
    return (unsigned short)r;
}

// Wave64 max-reduce of a non-negative f32 at VALU speed (DPP, no LDS hops).
__device__ __forceinline__ float wave_max_dpp(float v) {
#define DPP_MAX_STEP(ctrl)                                                     \
    v = fmaxf(v, __int_as_float(__builtin_amdgcn_update_dpp(                   \
               0, __float_as_int(v), (ctrl), 0xf, 0xf, true)))
    DPP_MAX_STEP(0xB1);   // quad_perm xor1
    DPP_MAX_STEP(0x4E);   // quad_perm xor2
    DPP_MAX_STEP(0x141);  // row_half_mirror xor4
    DPP_MAX_STEP(0x140);  // row_mirror xor8
    DPP_MAX_STEP(0x142);  // row_bcast15
    DPP_MAX_STEP(0x143);  // row_bcast31
#undef DPP_MAX_STEP
    return __int_as_float(__builtin_amdgcn_readlane(__float_as_int(v), 63));
}

// ---------------------------------------------------------------------------
// Kernel 0: weight prep. Transposes the 9 f32 [k][n] weights into bf16 [n][SW]
// zero-padded MFMA-B layout + copies biases (f32) into workspace. Runs once
// per launch, 9 blocks, ~µs. Makes every mlp block's weight access a direct
// L1/L2-resident global bf16x8 fragment load (no per-block staging VALU).
// ---------------------------------------------------------------------------
struct WPack { const float* w[9]; const float* b[9]; };

__global__ __launch_bounds__(256) void prep_weights(WPack p,
                                                    unsigned short* __restrict__ wout,
                                                    float* __restrict__ bout) {
    constexpr int cin[9]  = {67, 32, 32,  67, 64, 64,  67, 64, 96};
    constexpr int cout[9] = {32, 32, 64,  64, 64, 128, 64, 96, 128};
    constexpr int sw[9]   = {104, 40, 40, 104, 72, 72, 104, 72, 104};
    constexpr int woff[9] = {0, 3328, 4608, 7168, 13824, 18432, 27648, 34304, 41216};
    constexpr int boff[9] = {0, 32, 64, 128, 192, 256, 384, 448, 544};
    const int L = blockIdx.x;
    const float* w = p.w[L];
    const int ci = cin[L], co = cout[L], s = sw[L];
    unsigned short* dst = wout + woff[L];
    for (int e = threadIdx.x; e < co * s; e += 256) {
        const int n = e / s, k = e % s;
        dst[e] = (k < ci) ? f2bf(w[(size_t)k * co + n]) : (unsigned short)0;
    }
    for (int e = threadIdx.x; e < co; e += 256) bout[boff[L] + e] = p.b[L][e];
}

// ---------------------------------------------------------------------------
// Kernel 1: farthest point sampling (f32 I/O). One block per batch.
// R4 skeleton + pk-f32 distance update. At structural floor (R7 post-mortem).
// ---------------------------------------------------------------------------
__global__ __launch_bounds__(256) void fps_kernel(const float* __restrict__ xyz,
                                                  float* __restrict__ newxyz) {
#pragma clang fp contract(off)
    const int b = blockIdx.x;
    const int t = threadIdx.x;
    const int lane = t & 63;
    const int wave = t >> 6;
    __shared__ float xs[4096], ys[4096], zs[4096];
    __shared__ __align__(16) u64 skey[2][4];

    f32x2 px[8], py[8], pz[8], dist[8];
    {
        union { float4 v[12]; float f[48]; } u;
        const float4* src =
            reinterpret_cast<const float4*>(xyz + (size_t)b * 12288) + t * 12;
#pragma unroll
        for (int w = 0; w < 12; ++w) u.v[w] = src[w];
#pragma unroll
        for (int i = 0; i < 8; ++i) {
            px[i] = (f32x2){u.f[6 * i + 0], u.f[6 * i + 3]};
            py[i] = (f32x2){u.f[6 * i + 1], u.f[6 * i + 4]};
            pz[i] = (f32x2){u.f[6 * i + 2], u.f[6 * i + 5]};
            dist[i] = (f32x2){1e10f, 1e10f};
            const int j = t * 16 + 2 * i;
            xs[j] = px[i].x; xs[j + 1] = px[i].y;
            ys[j] = py[i].x; ys[j + 1] = py[i].y;
            zs[j] = pz[i].x; zs[j + 1] = pz[i].y;
        }
    }
    __syncthreads();

    int far = 0;
    for (int k = 0; k < 1024; ++k) {
        const float cx = xs[far], cy = ys[far], cz = zs[far];
        if (t == 0) {
            const size_t o = ((size_t)b * 1024 + k) * 3;
            newxyz[o + 0] = cx; newxyz[o + 1] = cy; newxyz[o + 2] = cz;
        }
        const f32x2 c2x = (f32x2){cx, cx};
        const f32x2 c2y = (f32x2){cy, cy};
        const f32x2 c2z = (f32x2){cz, cz};
#pragma unroll
        for (int i = 0; i < 8; ++i) {
            const f32x2 dx = px[i] - c2x;
            const f32x2 dy = py[i] - c2y;
            const f32x2 dz = pz[i] - c2z;
            const f32x2 s = dx * dx + dy * dy;   // pk_mul + pk_add (no fma)
            const f32x2 d = s + dz * dz;
            dist[i].x = fminf(dist[i].x, d.x);
            dist[i].y = fminf(dist[i].y, d.y);
        }
        float dv[16];
#pragma unroll
        for (int i = 0; i < 8; ++i) { dv[2 * i] = dist[i].x; dv[2 * i + 1] = dist[i].y; }
        float m8[8], m4[4], bv;
#pragma unroll
        for (int i = 0; i < 8; ++i) m8[i] = fmaxf(dv[i], dv[i + 8]);
#pragma unroll
        for (int i = 0; i < 4; ++i) m4[i] = fmaxf(m8[i], m8[i + 4]);
        bv = fmaxf(fmaxf(m4[0], m4[1]), fmaxf(m4[2], m4[3]));
        int bj = 15;
#pragma unroll
        for (int i = 14; i >= 0; --i) bj = (dv[i] == bv) ? i : bj;
        const int myidx = t * 16 + bj;

        const float wmax = wave_max_dpp(bv);
        const u64 mask = __ballot(bv == wmax);
        const int fl = (int)__builtin_ctzll(mask);
        const int widx = __builtin_amdgcn_readlane(myidx, fl);

        const int p = k & 1;
        if (lane == 0)
            skey[p][wave] =
                ((u64)__float_as_uint(wmax) << 32) | (unsigned)(4095 - widx);
        __syncthreads();
        const ulonglong2 ka = *reinterpret_cast<const ulonglong2*>(&skey[p][0]);
        const ulonglong2 kb = *reinterpret_cast<const ulonglong2*>(&skey[p][2]);
        const u64 m01 = (ka.x > ka.y) ? ka.x : ka.y;
        const u64 m23 = (kb.x > kb.y) ? kb.x : kb.y;
        const u64 mm = (m01 > m23) ? m01 : m23;
        far = 4095 - (int)(unsigned)(mm & 0xffffffffull);
    }
}

// ---------------------------------------------------------------------------
// Kernel 2: ball query, all 3 radii in one pass (f32 in, u16 idx out).
// ---------------------------------------------------------------------------
__global__ __launch_bounds__(256) void ballq_kernel(const float* __restrict__ xyz,
                                                    const float* __restrict__ newxyz,
                                                    unsigned short* __restrict__ idx0,
                                                    unsigned short* __restrict__ idx1,
                                                    unsigned short* __restrict__ idx2) {
    const int wave = threadIdx.x >> 6;
    const int lane = threadIdx.x & 63;
    const int g = blockIdx.x * 4 + wave;   // g = b*1024 + s
    const int b = g >> 10;

    const float* nc = newxyz + (size_t)g * 3;
    const float cx = nc[0], cy = nc[1], cz = nc[2];

    int cnt0 = 0, cnt1 = 0, cnt2 = 0;
    int f0 = 0, f1 = 0, f2 = 0;
    unsigned short* o0 = idx0 + (size_t)g * 16;
    unsigned short* o1 = idx1 + (size_t)g * 32;
    unsigned short* o2 = idx2 + (size_t)g * 128;
    const float* base = xyz + (size_t)b * 12288;

    for (int it = 0; it < 64; ++it) {
        const int j = it * 64 + lane;
        const float* p = base + j * 3;
        const float dx = p[0] - cx;
        const float dy = p[1] - cy;
        const float dz = p[2] - cz;
        const float d2 = __fadd_rn(__fadd_rn(__fmul_rn(dx, dx), __fmul_rn(dy, dy)),
                                   __fmul_rn(dz, dz));
        const bool p0 = d2 < 0.01f;
        const bool p1 = d2 < 0.04f;
        const bool p2 = d2 < 0.16f;
        const u64 m0 = __ballot(p0);
        const u64 m1 = __ballot(p1);
        const u64 m2 = __ballot(p2);
        const u64 lower = (((u64)1) << lane) - 1;

        if (cnt0 < 16) {
            if (cnt0 == 0 && m0) f0 = it * 64 + __builtin_ctzll(m0);
            const int pos = cnt0 + (int)__builtin_popcountll(m0 & lower);
            if (p0 && pos < 16) o0[pos] = (unsigned short)j;
            cnt0 += (int)__builtin_popcountll(m0);
        }
        if (cnt1 < 32) {
            if (cnt1 == 0 && m1) f1 = it * 64 + __builtin_ctzll(m1);
            const int pos = cnt1 + (int)__builtin_popcountll(m1 & lower);
            if (p1 && pos < 32) o1[pos] = (unsigned short)j;
            cnt1 += (int)__builtin_popcountll(m1);
        }
        if (cnt2 < 128) {
            if (cnt2 == 0 && m2) f2 = it * 64 + __builtin_ctzll(m2);
            const int pos = cnt2 + (int)__builtin_popcountll(m2 & lower);
            if (p2 && pos < 128) o2[pos] = (unsigned short)j;
            cnt2 += (int)__builtin_popcountll(m2);
        }
        if (cnt0 >= 16 && cnt1 >= 32 && cnt2 >= 128) break;
    }
    for (int pos = cnt0 + lane; pos < 16; pos += 64) o0[pos] = (unsigned short)f0;
    for (int pos = cnt1 + lane; pos < 32; pos += 64) o1[pos] = (unsigned short)f1;
    for (int pos = cnt2 + lane; pos < 128; pos += 64) o2[pos] = (unsigned short)f2;
}

// ---------------------------------------------------------------------------
// One wave computes MW rows x Cout cols of one layer. A from LDS; B-fragments
// + bias straight from prepped global (bf16 [n][SW], L1/L2-resident).
// A (m89/m120): A[m=lane&15][k=quad*8+j]; B: n=lane&15, k=quad*8+j;
// C/D: col=lane&15, row=quad*4+reg.
// ---------------------------------------------------------------------------
template <int MW, int Kp, int Cout, int SIN, int SW, int SOUT, bool LAST>
__device__ __forceinline__ void layer_mfma(const unsigned short* __restrict__ src,
                                           unsigned short* __restrict__ dst,
                                           const unsigned short* __restrict__ Wg,
                                           const float* __restrict__ bg,
                                           float* __restrict__ Mx,
                                           int lane, int mslice) {
    constexpr int MT = MW / 16;
    constexpr int NT = Cout / 16;
    const int ml = lane & 15;
    const int quad = lane >> 4;

    f32x4 acc[MT][NT];
#pragma unroll
    for (int mt = 0; mt < MT; ++mt)
#pragma unroll
        for (int nt = 0; nt < NT; ++nt) acc[mt][nt] = (f32x4){0.f, 0.f, 0.f, 0.f};

#pragma unroll
    for (int ks = 0; ks < Kp; ks += 32) {
        bf16x8 afr[MT], bfr[NT];
#pragma unroll
        for (int mt = 0; mt < MT; ++mt)
            afr[mt] = *reinterpret_cast<const bf16x8*>(
                src + (mslice * MW + mt * 16 + ml) * SIN + ks + quad * 8);
#pragma unroll
        for (int nt = 0; nt < NT; ++nt)
            bfr[nt] = *reinterpret_cast<const bf16x8*>(
                Wg + (nt * 16 + ml) * SW + ks + quad * 8);
#pragma unroll
        for (int mt = 0; mt < MT; ++mt)
#pragma unroll
            for (int nt = 0; nt < NT; ++nt)
                acc[mt][nt] = __builtin_amdgcn_mfma_f32_16x16x32_bf16(
                    afr[mt], bfr[nt], acc[mt][nt], 0, 0, 0);
    }

#pragma unroll
    for (int nt = 0; nt < NT; ++nt) {
        const int col = nt * 16 + ml;
        const float bv = bg[col];
        if constexpr (!LAST) {
#pragma unroll
            for (int mt = 0; mt < MT; ++mt)
#pragma unroll
                for (int r = 0; r < 4; ++r) {
                    const float v = fmaxf(acc[mt][nt][r] + bv, 0.0f);
                    dst[(mslice * MW + mt * 16 + quad * 4 + r) * SOUT + col] = f2bf(v);
                }
        } else {
            float mx = 0.0f;   // relu floor folds into the max
#pragma unroll
            for (int mt = 0; mt < MT; ++mt)
#pragma unroll
                for (int r = 0; r < 4; ++r) mx = fmaxf(mx, acc[mt][nt][r] + bv);
            mx = fmaxf(mx, __shfl_xor(mx, 16, 64));
            mx = fmaxf(mx, __shfl_xor(mx, 32, 64));
            if (quad == 0)
                atomicMax(reinterpret_cast<int*>(Mx + col), __float_as_int(mx));
        }
    }
}

// ---------------------------------------------------------------------------
// Kernel 3: grouping + 3-layer MLP + max-pool. Weights pre-transposed in ws.
// Barriers only at genuine cross-thread hand-offs (gather, final Mx).
// ---------------------------------------------------------------------------
template <int NS, int C1, int C2, int C3, int NG, int WPG, int CH_OFF>
__global__ __launch_bounds__(256) void mlp_kernel(
    const float* __restrict__ xyz,
    const float* __restrict__ points,
    const float* __restrict__ newxyz,
    const unsigned short* __restrict__ idx,
    const unsigned short* __restrict__ wg1, const unsigned short* __restrict__ wg2,
    const unsigned short* __restrict__ wg3,
    const float* __restrict__ bg1, const float* __restrict__ bg2,
    const float* __restrict__ bg3,
    float* __restrict__ outfeat) {
    constexpr int SA = 104;            // stride for 96-wide A buffer (+8 pad)
    constexpr int SB = C1 + 8;
    constexpr int SW1 = 104, SW2 = C1 + 8, SW3 = C2 + 8;
    constexpr int MW = NS / WPG;

    __shared__ __align__(16) unsigned short Abuf[NG][NS][SA];
    __shared__ __align__(16) unsigned short Bbuf[NG][NS][SB];
    __shared__ float Mx[NG][C3];
    __shared__ unsigned short idxbuf[NG][NS];

    const int tid = threadIdx.x;
    const int lane = tid & 63;
    const int wave = tid >> 6;
    const int gl = wave / WPG;
    const int mslice = wave % WPG;

    for (int e = tid; e < NG * NS; e += 256)
        (&idxbuf[0][0])[e] = idx[(size_t)blockIdx.x * (NG * NS) + e];
    for (int e = tid; e < NG * C3; e += 256) (&Mx[0][0])[e] = 0.0f;
    __syncthreads();

    // gather: 4 threads per row (16 channels each); q==3 adds g_xyz + zero pad
    for (int rr = tid >> 2; rr < NG * NS; rr += 64) {
        const int q = tid & 3;
        const int g = rr / NS, kk = rr % NS;
        const int gg = blockIdx.x * NG + g;
        const int bb = gg >> 10;
        const int id = idxbuf[g][kk] & 4095;
        const float4* s4 = reinterpret_cast<const float4*>(
            points + (((size_t)bb * 4096 + id) << 6) + q * 16);
        const float4 c0 = s4[0], c1 = s4[1], c2 = s4[2], c3 = s4[3];
        union { uint4 o[2]; unsigned short h[16]; } t16;
        const float cc[16] = {c0.x, c0.y, c0.z, c0.w, c1.x, c1.y, c1.z, c1.w,
                              c2.x, c2.y, c2.z, c2.w, c3.x, c3.y, c3.z, c3.w};
#pragma unroll
        for (int i = 0; i < 16; ++i) t16.h[i] = f2bf(cc[i]);
        *reinterpret_cast<uint4*>(&Abuf[g][kk][q * 16]) = t16.o[0];
        *reinterpret_cast<uint4*>(&Abuf[g][kk][q * 16 + 8]) = t16.o[1];
        if (q == 3) {
            const float* pz = xyz + ((size_t)bb * 4096 + id) * 3;
            const float* nc = newxyz + (size_t)gg * 3;
            Abuf[g][kk][64] = f2bf(pz[0] - nc[0]);
            Abuf[g][kk][65] = f2bf(pz[1] - nc[1]);
            Abuf[g][kk][66] = f2bf(pz[2] - nc[2]);
#pragma unroll
            for (int c = 67; c < 72; ++c) Abuf[g][kk][c] = 0;
            *reinterpret_cast<uint4*>(&Abuf[g][kk][72]) = (uint4){0, 0, 0, 0};
            *reinterpret_cast<uint4*>(&Abuf[g][kk][80]) = (uint4){0, 0, 0, 0};
            *reinterpret_cast<uint4*>(&Abuf[g][kk][88]) = (uint4){0, 0, 0, 0};
        }
    }
    __syncthreads();

    // L1: 96(67) -> C1 ; L2: C1 -> C2 ; L3: C2 -> C3 (fused bias+relu+max).
    // No barriers: each wave owns its MW rows end-to-end.
    layer_mfma<MW, 96, C1, SA, SW1, SB, false>(&Abuf[gl][0][0], &Bbuf[gl][0][0],
                                               wg1, bg1, nullptr, lane, mslice);
    layer_mfma<MW, C1, C2, SB, SW2, SA, false>(&Bbuf[gl][0][0], &Abuf[gl][0][0],
                                               wg2, bg2, nullptr, lane, mslice);
    layer_mfma<MW, C2, C3, SA, SW3, 0, true>(&Abuf[gl][0][0], nullptr,
                                             wg3, bg3, &Mx[gl][0], lane, mslice);
    __syncthreads();

    for (int e = tid; e < NG * C3; e += 256) {
        const int g = e / C3, c = e % C3;
        const size_t gg = (size_t)blockIdx.x * NG + g;
        outfeat[gg * 320 + CH_OFF + c] = (&Mx[0][0])[e];
    }
}

// ---------------------------------------------------------------------------
extern "C" void kernel_launch(void* const* d_in, const int* in_sizes, int n_in,
                              void* d_out, int out_size, void* d_ws, size_t ws_size,
                              hipStream_t stream) {
    (void)in_sizes; (void)n_in; (void)out_size; (void)ws_size;
    const float* xyz = (const float*)d_in[0];
    const float* points = (const float*)d_in[1];
    WPack pack;
    int p = 2;
    for (int L = 0; L < 9; ++L) {
        pack.w[L] = (const float*)d_in[p++];
        pack.b[L] = (const float*)d_in[p++];
    }
    float* newxyz = (float*)d_out;                  // 8*1024*3
    float* outfeat = (float*)d_out + 8 * 1024 * 3;  // 8*1024*320

    unsigned short* wsu = (unsigned short*)d_ws;
    unsigned short* idx0 = wsu;                        // 8192*16
    unsigned short* idx1 = wsu + (size_t)8192 * 16;    // 8192*32
    unsigned short* idx2 = wsu + (size_t)8192 * 48;    // 8192*128
    unsigned short* wprep = wsu + (size_t)8192 * 176;  // 54528 bf16
    float* bprep = (float*)(wsu + (size_t)8192 * 176 + 54528 + 2 /*align pad*/);

    prep_weights<<<dim3(9), dim3(256), 0, stream>>>(pack, wprep, bprep);
    fps_kernel<<<dim3(8), dim3(256), 0, stream>>>(xyz, newxyz);
    ballq_kernel<<<dim3(2048), dim3(256), 0, stream>>>(xyz, newxyz, idx0, idx1, idx2);
    mlp_kernel<16, 32, 32, 64, 4, 1, 0><<<dim3(2048), dim3(256), 0, stream>>>(
        xyz, points, newxyz, idx0,
        wprep + 0, wprep + 3328, wprep + 4608,
        bprep + 0, bprep + 32, bprep + 64, outfeat);
    mlp_kernel<32, 64, 64, 128, 4, 1, 64><<<dim3(2048), dim3(256), 0, stream>>>(
        xyz, points, newxyz, idx1,
        wprep + 7168, wprep + 13824, wprep + 18432,
        bprep + 128, bprep + 192, bprep + 256, outfeat);
    mlp_kernel<128, 64, 96, 128, 1, 4, 192><<<dim3(8192), dim3(256), 0, stream>>>(
        xyz, points, newxyz, idx2,
        wprep + 27648, wprep + 34304, wprep + 41216,
        bprep + 384, bprep + 448, bprep + 544, outfeat);
}

// Round 9
// 884.464 us; speedup vs baseline: 1.7530x; 1.0034x over previous
//
#include <hip/hip_runtime.h>
#include <hip/hip_bf16.h>
#include <stdint.h>

typedef unsigned long long u64;
typedef __attribute__((ext_vector_type(8))) short bf16x8;   // 8 bf16 = 4 VGPRs
typedef __attribute__((ext_vector_type(4))) float f32x4;
typedef __attribute__((ext_vector_type(2))) float f32x2;    // v_pk_*_f32 pair

__device__ __forceinline__ unsigned short f2bf(float f) {
    unsigned x = __float_as_uint(f);
    unsigned r = (x + 0x7fffu + ((x >> 16) & 1u)) >> 16;   // RNE
    return (unsigned short)r;
}

// 8 f32 -> bf16x8 via packed RNE converts (v_cvt_pk_bf16_f32).
__device__ __forceinline__ bf16x8 cvt8(float4 a, float4 b) {
    union { bf16x8 v; __hip_bfloat162 h[4]; } u;
    u.h[0] = __float22bfloat162_rn({a.x, a.y});
    u.h[1] = __float22bfloat162_rn({a.z, a.w});
    u.h[2] = __float22bfloat162_rn({b.x, b.y});
    u.h[3] = __float22bfloat162_rn({b.z, b.w});
    return u.v;
}

// Wave64 max-reduce of a non-negative f32 at VALU speed (DPP, no LDS hops).
__device__ __forceinline__ float wave_max_dpp(float v) {
#define DPP_MAX_STEP(ctrl)                                                     \
    v = fmaxf(v, __int_as_float(__builtin_amdgcn_update_dpp(                   \
               0, __float_as_int(v), (ctrl), 0xf, 0xf, true)))
    DPP_MAX_STEP(0xB1);   // quad_perm xor1
    DPP_MAX_STEP(0x4E);   // quad_perm xor2
    DPP_MAX_STEP(0x141);  // row_half_mirror xor4
    DPP_MAX_STEP(0x140);  // row_mirror xor8
    DPP_MAX_STEP(0x142);  // row_bcast15
    DPP_MAX_STEP(0x143);  // row_bcast31
#undef DPP_MAX_STEP
    return __int_as_float(__builtin_amdgcn_readlane(__float_as_int(v), 63));
}

struct WPack { const float* w[9]; const float* b[9]; };

// ---------------------------------------------------------------------------
// Kernel 1: FPS (blocks 0..7) + weight prep (blocks 8..16, runs in the shadow
// of FPS on otherwise-idle CUs). FPS: R4 skeleton + pk-f32 distance update —
// at structural floor (R7). Prep: transpose 9 f32 [k][n] weights to bf16
// [n][SW] zero-padded MFMA-B layout + f32 biases into workspace.
// ---------------------------------------------------------------------------
__global__ __launch_bounds__(256) void fps_prep_kernel(
    const float* __restrict__ xyz, float* __restrict__ newxyz, WPack p,
    unsigned short* __restrict__ wout, float* __restrict__ bout) {
#pragma clang fp contract(off)
    if (blockIdx.x >= 8) {   // ---- prep path ----
        constexpr int cin[9]  = {67, 32, 32,  67, 64, 64,  67, 64, 96};
        constexpr int cout[9] = {32, 32, 64,  64, 64, 128, 64, 96, 128};
        constexpr int sw[9]   = {104, 40, 40, 104, 72, 72, 104, 72, 104};
        constexpr int woff[9] = {0, 3328, 4608, 7168, 13824, 18432, 27648, 34304, 41216};
        constexpr int boff[9] = {0, 32, 64, 128, 192, 256, 384, 448, 544};
        const int L = blockIdx.x - 8;
        const float* w = p.w[L];
        const int ci = cin[L], co = cout[L], s = sw[L];
        unsigned short* dst = wout + woff[L];
        for (int e = threadIdx.x; e < co * s; e += 256) {
            const int n = e / s, k = e % s;
            dst[e] = (k < ci) ? f2bf(w[(size_t)k * co + n]) : (unsigned short)0;
        }
        for (int e = threadIdx.x; e < co; e += 256) bout[boff[L] + e] = p.b[L][e];
        return;
    }
    // ---- fps path ----
    const int b = blockIdx.x;
    const int t = threadIdx.x;
    const int lane = t & 63;
    const int wave = t >> 6;
    __shared__ float xs[4096], ys[4096], zs[4096];
    __shared__ __align__(16) u64 skey[2][4];

    f32x2 px[8], py[8], pz[8], dist[8];
    {
        union { float4 v[12]; float f[48]; } u;
        const float4* src =
            reinterpret_cast<const float4*>(xyz + (size_t)b * 12288) + t * 12;
#pragma unroll
        for (int w = 0; w < 12; ++w) u.v[w] = src[w];
#pragma unroll
        for (int i = 0; i < 8; ++i) {
            px[i] = (f32x2){u.f[6 * i + 0], u.f[6 * i + 3]};
            py[i] = (f32x2){u.f[6 * i + 1], u.f[6 * i + 4]};
            pz[i] = (f32x2){u.f[6 * i + 2], u.f[6 * i + 5]};
            dist[i] = (f32x2){1e10f, 1e10f};
            const int j = t * 16 + 2 * i;
            xs[j] = px[i].x; xs[j + 1] = px[i].y;
            ys[j] = py[i].x; ys[j + 1] = py[i].y;
            zs[j] = pz[i].x; zs[j + 1] = pz[i].y;
        }
    }
    __syncthreads();

    int far = 0;
    for (int k = 0; k < 1024; ++k) {
        const float cx = xs[far], cy = ys[far], cz = zs[far];
        if (t == 0) {
            const size_t o = ((size_t)b * 1024 + k) * 3;
            newxyz[o + 0] = cx; newxyz[o + 1] = cy; newxyz[o + 2] = cz;
        }
        const f32x2 c2x = (f32x2){cx, cx};
        const f32x2 c2y = (f32x2){cy, cy};
        const f32x2 c2z = (f32x2){cz, cz};
#pragma unroll
        for (int i = 0; i < 8; ++i) {
            const f32x2 dx = px[i] - c2x;
            const f32x2 dy = py[i] - c2y;
            const f32x2 dz = pz[i] - c2z;
            const f32x2 s = dx * dx + dy * dy;   // pk_mul + pk_add (no fma)
            const f32x2 d = s + dz * dz;
            dist[i].x = fminf(dist[i].x, d.x);
            dist[i].y = fminf(dist[i].y, d.y);
        }
        float dv[16];
#pragma unroll
        for (int i = 0; i < 8; ++i) { dv[2 * i] = dist[i].x; dv[2 * i + 1] = dist[i].y; }
        float m8[8], m4[4], bv;
#pragma unroll
        for (int i = 0; i < 8; ++i) m8[i] = fmaxf(dv[i], dv[i + 8]);
#pragma unroll
        for (int i = 0; i < 4; ++i) m4[i] = fmaxf(m8[i], m8[i + 4]);
        bv = fmaxf(fmaxf(m4[0], m4[1]), fmaxf(m4[2], m4[3]));
        int bj = 15;
#pragma unroll
        for (int i = 14; i >= 0; --i) bj = (dv[i] == bv) ? i : bj;
        const int myidx = t * 16 + bj;

        const float wmax = wave_max_dpp(bv);
        const u64 mask = __ballot(bv == wmax);
        const int fl = (int)__builtin_ctzll(mask);
        const int widx = __builtin_amdgcn_readlane(myidx, fl);

        const int pp = k & 1;
        if (lane == 0)
            skey[pp][wave] =
                ((u64)__float_as_uint(wmax) << 32) | (unsigned)(4095 - widx);
        __syncthreads();
        const ulonglong2 ka = *reinterpret_cast<const ulonglong2*>(&skey[pp][0]);
        const ulonglong2 kb = *reinterpret_cast<const ulonglong2*>(&skey[pp][2]);
        const u64 m01 = (ka.x > ka.y) ? ka.x : ka.y;
        const u64 m23 = (kb.x > kb.y) ? kb.x : kb.y;
        const u64 mm = (m01 > m23) ? m01 : m23;
        far = 4095 - (int)(unsigned)(mm & 0xffffffffull);
    }
}

// ---------------------------------------------------------------------------
// Kernel 2: ball query, all 3 radii in one pass (f32 in, u16 idx out).
// ---------------------------------------------------------------------------
__global__ __launch_bounds__(256) void ballq_kernel(const float* __restrict__ xyz,
                                                    const float* __restrict__ newxyz,
                                                    unsigned short* __restrict__ idx0,
                                                    unsigned short* __restrict__ idx1,
                                                    unsigned short* __restrict__ idx2) {
    const int wave = threadIdx.x >> 6;
    const int lane = threadIdx.x & 63;
    const int g = blockIdx.x * 4 + wave;   // g = b*1024 + s
    const int b = g >> 10;

    const float* nc = newxyz + (size_t)g * 3;
    const float cx = nc[0], cy = nc[1], cz = nc[2];

    int cnt0 = 0, cnt1 = 0, cnt2 = 0;
    int f0 = 0, f1 = 0, f2 = 0;
    unsigned short* o0 = idx0 + (size_t)g * 16;
    unsigned short* o1 = idx1 + (size_t)g * 32;
    unsigned short* o2 = idx2 + (size_t)g * 128;
    const float* base = xyz + (size_t)b * 12288;

    for (int it = 0; it < 64; ++it) {
        const int j = it * 64 + lane;
        const float* p = base + j * 3;
        const float dx = p[0] - cx;
        const float dy = p[1] - cy;
        const float dz = p[2] - cz;
        const float d2 = __fadd_rn(__fadd_rn(__fmul_rn(dx, dx), __fmul_rn(dy, dy)),
                                   __fmul_rn(dz, dz));
        const bool p0 = d2 < 0.01f;
        const bool p1 = d2 < 0.04f;
        const bool p2 = d2 < 0.16f;
        const u64 m0 = __ballot(p0);
        const u64 m1 = __ballot(p1);
        const u64 m2 = __ballot(p2);
        const u64 lower = (((u64)1) << lane) - 1;

        if (cnt0 < 16) {
            if (cnt0 == 0 && m0) f0 = it * 64 + __builtin_ctzll(m0);
            const int pos = cnt0 + (int)__builtin_popcountll(m0 & lower);
            if (p0 && pos < 16) o0[pos] = (unsigned short)j;
            cnt0 += (int)__builtin_popcountll(m0);
        }
        if (cnt1 < 32) {
            if (cnt1 == 0 && m1) f1 = it * 64 + __builtin_ctzll(m1);
            const int pos = cnt1 + (int)__builtin_popcountll(m1 & lower);
            if (p1 && pos < 32) o1[pos] = (unsigned short)j;
            cnt1 += (int)__builtin_popcountll(m1);
        }
        if (cnt2 < 128) {
            if (cnt2 == 0 && m2) f2 = it * 64 + __builtin_ctzll(m2);
            const int pos = cnt2 + (int)__builtin_popcountll(m2 & lower);
            if (p2 && pos < 128) o2[pos] = (unsigned short)j;
            cnt2 += (int)__builtin_popcountll(m2);
        }
        if (cnt0 >= 16 && cnt1 >= 32 && cnt2 >= 128) break;
    }
    for (int pos = cnt0 + lane; pos < 16; pos += 64) o0[pos] = (unsigned short)f0;
    for (int pos = cnt1 + lane; pos < 32; pos += 64) o1[pos] = (unsigned short)f1;
    for (int pos = cnt2 + lane; pos < 128; pos += 64) o2[pos] = (unsigned short)f2;
}

// ---------------------------------------------------------------------------
// Layer 1, A-fragments DIRECT from global points (no LDS staging, no gather):
// lane(m=lane&15, q=lane>>4) holds channels ks+q*8..+7 of its point rows.
// ks=64 frag: quad0 = {g_xyz, 0...}, quads 1-3 = 0 (channel pad).
// ---------------------------------------------------------------------------
template <int MW, int Cout, int SOUT>
__device__ __forceinline__ void layer1_direct(
    const float* __restrict__ pts,        // points + bb*4096*64
    const float* __restrict__ xyzb,       // xyz + bb*12288
    const unsigned short* __restrict__ idxb,  // LDS, NS entries for this group
    float ncx, float ncy, float ncz,
    const unsigned short* __restrict__ Wg, const float* __restrict__ bg,
    unsigned short* __restrict__ dst, int lane, int mslice) {
    constexpr int SW = 104;
    constexpr int MT = MW / 16;
    constexpr int NT = Cout / 16;
    const int ml = lane & 15;
    const int quad = lane >> 4;

    bf16x8 afr[MT][3];
#pragma unroll
    for (int mt = 0; mt < MT; ++mt) {
        const int row = mslice * MW + mt * 16 + ml;
        const int id = idxb[row] & 4095;
        const float* rb = pts + ((size_t)id << 6) + quad * 8;
        const float4* r4 = reinterpret_cast<const float4*>(rb);
        afr[mt][0] = cvt8(r4[0], r4[1]);
        const float4* r4b = reinterpret_cast<const float4*>(rb + 32);
        afr[mt][1] = cvt8(r4b[0], r4b[1]);
        union { bf16x8 v; unsigned short h[8]; } tg;
        tg.v = (bf16x8)(short)0;
        if (quad == 0) {
            const float* pz = xyzb + (size_t)id * 3;
            tg.h[0] = f2bf(pz[0] - ncx);
            tg.h[1] = f2bf(pz[1] - ncy);
            tg.h[2] = f2bf(pz[2] - ncz);
        }
        afr[mt][2] = tg.v;
    }

    f32x4 acc[MT][NT];
#pragma unroll
    for (int mt = 0; mt < MT; ++mt)
#pragma unroll
        for (int nt = 0; nt < NT; ++nt) acc[mt][nt] = (f32x4){0.f, 0.f, 0.f, 0.f};

#pragma unroll
    for (int ks = 0; ks < 3; ++ks) {
        bf16x8 bfr[NT];
#pragma unroll
        for (int nt = 0; nt < NT; ++nt)
            bfr[nt] = *reinterpret_cast<const bf16x8*>(
                Wg + (nt * 16 + ml) * SW + ks * 32 + quad * 8);
#pragma unroll
        for (int mt = 0; mt < MT; ++mt)
#pragma unroll
            for (int nt = 0; nt < NT; ++nt)
                acc[mt][nt] = __builtin_amdgcn_mfma_f32_16x16x32_bf16(
                    afr[mt][ks], bfr[nt], acc[mt][nt], 0, 0, 0);
    }

#pragma unroll
    for (int nt = 0; nt < NT; ++nt) {
        const int col = nt * 16 + ml;
        const float bv = bg[col];
#pragma unroll
        for (int mt = 0; mt < MT; ++mt)
#pragma unroll
            for (int r = 0; r < 4; ++r) {
                const float v = fmaxf(acc[mt][nt][r] + bv, 0.0f);
                dst[(mslice * MW + mt * 16 + quad * 4 + r) * SOUT + col] = f2bf(v);
            }
    }
}

// Layers 2/3: A from LDS, B-fragments + bias from prepped global.
template <int MW, int Kp, int Cout, int SIN, int SW, int SOUT, bool LAST>
__device__ __forceinline__ void layer_lds(const unsigned short* __restrict__ src,
                                          unsigned short* __restrict__ dst,
                                          const unsigned short* __restrict__ Wg,
                                          const float* __restrict__ bg,
                                          float* __restrict__ Mx,
                                          int lane, int mslice) {
    constexpr int MT = MW / 16;
    constexpr int NT = Cout / 16;
    const int ml = lane & 15;
    const int quad = lane >> 4;

    f32x4 acc[MT][NT];
#pragma unroll
    for (int mt = 0; mt < MT; ++mt)
#pragma unroll
        for (int nt = 0; nt < NT; ++nt) acc[mt][nt] = (f32x4){0.f, 0.f, 0.f, 0.f};

#pragma unroll
    for (int ks = 0; ks < Kp; ks += 32) {
        bf16x8 afr[MT], bfr[NT];
#pragma unroll
        for (int mt = 0; mt < MT; ++mt)
            afr[mt] = *reinterpret_cast<const bf16x8*>(
                src + (mslice * MW + mt * 16 + ml) * SIN + ks + quad * 8);
#pragma unroll
        for (int nt = 0; nt < NT; ++nt)
            bfr[nt] = *reinterpret_cast<const bf16x8*>(
                Wg + (nt * 16 + ml) * SW + ks + quad * 8);
#pragma unroll
        for (int mt = 0; mt < MT; ++mt)
#pragma unroll
            for (int nt = 0; nt < NT; ++nt)
                acc[mt][nt] = __builtin_amdgcn_mfma_f32_16x16x32_bf16(
                    afr[mt], bfr[nt], acc[mt][nt], 0, 0, 0);
    }

#pragma unroll
    for (int nt = 0; nt < NT; ++nt) {
        const int col = nt * 16 + ml;
        const float bv = bg[col];
        if constexpr (!LAST) {
#pragma unroll
            for (int mt = 0; mt < MT; ++mt)
#pragma unroll
                for (int r = 0; r < 4; ++r) {
                    const float v = fmaxf(acc[mt][nt][r] + bv, 0.0f);
                    dst[(mslice * MW + mt * 16 + quad * 4 + r) * SOUT + col] = f2bf(v);
                }
        } else {
            float mx = 0.0f;   // relu floor folds into the max
#pragma unroll
            for (int mt = 0; mt < MT; ++mt)
#pragma unroll
                for (int r = 0; r < 4; ++r) mx = fmaxf(mx, acc[mt][nt][r] + bv);
            mx = fmaxf(mx, __shfl_xor(mx, 16, 64));
            mx = fmaxf(mx, __shfl_xor(mx, 32, 64));
            if (quad == 0)
                atomicMax(reinterpret_cast<int*>(Mx + col), __float_as_int(mx));
        }
    }
}

// ---------------------------------------------------------------------------
// Kernel 3: 3-layer MLP + max-pool. L1 A direct from global; no gather phase.
// ---------------------------------------------------------------------------
template <int NS, int C1, int C2, int C3, int NG, int WPG, int CH_OFF>
__global__ __launch_bounds__(256) void mlp_kernel(
    const float* __restrict__ xyz,
    const float* __restrict__ points,
    const float* __restrict__ newxyz,
    const unsigned short* __restrict__ idx,
    const unsigned short* __restrict__ wg1, const unsigned short* __restrict__ wg2,
    const unsigned short* __restrict__ wg3,
    const float* __restrict__ bg1, const float* __restrict__ bg2,
    const float* __restrict__ bg3,
    float* __restrict__ outfeat) {
    constexpr int SB = C1 + 8;
    constexpr int SC = C2 + 8;
    constexpr int MW = NS / WPG;

    __shared__ __align__(16) unsigned short Bbuf[NG][NS][SB];
    __shared__ __align__(16) unsigned short Cbuf[NG][NS][SC];
    __shared__ float Mx[NG][C3];
    __shared__ unsigned short idxbuf[NG * NS];

    const int tid = threadIdx.x;
    const int lane = tid & 63;
    const int wave = tid >> 6;
    const int gl = wave / WPG;
    const int mslice = wave % WPG;

    for (int e = tid; e < NG * NS; e += 256)
        idxbuf[e] = idx[(size_t)blockIdx.x * (NG * NS) + e];
    for (int e = tid; e < NG * C3; e += 256) (&Mx[0][0])[e] = 0.0f;
    __syncthreads();

    const int gg = blockIdx.x * NG + gl;
    const int bb = gg >> 10;
    const float* nc = newxyz + (size_t)gg * 3;
    const float ncx = nc[0], ncy = nc[1], ncz = nc[2];

    layer1_direct<MW, C1, SB>(points + ((size_t)bb << 18), xyz + (size_t)bb * 12288,
                              &idxbuf[gl * NS], ncx, ncy, ncz, wg1, bg1,
                              &Bbuf[gl][0][0], lane, mslice);
    layer_lds<MW, C1, C2, SB, C1 + 8, SC, false>(&Bbuf[gl][0][0], &Cbuf[gl][0][0],
                                                 wg2, bg2, nullptr, lane, mslice);
    layer_lds<MW, C2, C3, SC, C2 + 8, 0, true>(&Cbuf[gl][0][0], nullptr,
                                               wg3, bg3, &Mx[gl][0], lane, mslice);
    __syncthreads();

    for (int e = tid; e < NG * C3; e += 256) {
        const int g = e / C3, c = e % C3;
        const size_t g2 = (size_t)blockIdx.x * NG + g;
        outfeat[g2 * 320 + CH_OFF + c] = (&Mx[0][0])[e];
    }
}

// ---------------------------------------------------------------------------
extern "C" void kernel_launch(void* const* d_in, const int* in_sizes, int n_in,
                              void* d_out, int out_size, void* d_ws, size_t ws_size,
                              hipStream_t stream) {
    (void)in_sizes; (void)n_in; (void)out_size; (void)ws_size;
    const float* xyz = (const float*)d_in[0];
    const float* points = (const float*)d_in[1];
    WPack pack;
    int p = 2;
    for (int L = 0; L < 9; ++L) {
        pack.w[L] = (const float*)d_in[p++];
        pack.b[L] = (const float*)d_in[p++];
    }
    float* newxyz = (float*)d_out;                  // 8*1024*3
    float* outfeat = (float*)d_out + 8 * 1024 * 3;  // 8*1024*320

    unsigned short* wsu = (unsigned short*)d_ws;
    unsigned short* idx0 = wsu;                        // 8192*16
    unsigned short* idx1 = wsu + (size_t)8192 * 16;    // 8192*32
    unsigned short* idx2 = wsu + (size_t)8192 * 48;    // 8192*128
    unsigned short* wprep = wsu + (size_t)8192 * 176;  // 54528 bf16
    float* bprep = (float*)(wsu + (size_t)8192 * 176 + 54528 + 2 /*align pad*/);

    fps_prep_kernel<<<dim3(17), dim3(256), 0, stream>>>(xyz, newxyz, pack, wprep, bprep);
    ballq_kernel<<<dim3(2048), dim3(256), 0, stream>>>(xyz, newxyz, idx0, idx1, idx2);
    mlp_kernel<16, 32, 32, 64, 4, 1, 0><<<dim3(2048), dim3(256), 0, stream>>>(
        xyz, points, newxyz, idx0,
        wprep + 0, wprep + 3328, wprep + 4608,
        bprep + 0, bprep + 32, bprep + 64, outfeat);
    mlp_kernel<32, 64, 64, 128, 4, 1, 64><<<dim3(2048), dim3(256), 0, stream>>>(
        xyz, points, newxyz, idx1,
        wprep + 7168, wprep + 13824, wprep + 18432,
        bprep + 128, bprep + 192, bprep + 256, outfeat);
    mlp_kernel<128, 64, 96, 128, 1, 4, 192><<<dim3(8192), dim3(256), 0, stream>>>(
        xyz, points, newxyz, idx2,
        wprep + 27648, wprep + 34304, wprep + 41216,
        bprep + 384, bprep + 448, bprep + 544, outfeat);
}